// Round 8
// baseline (291.129 us; speedup 1.0000x reference)
//
#include <hip/hip_runtime.h>
#include <hip/hip_bf16.h>

typedef __attribute__((ext_vector_type(8))) short short8;
typedef __attribute__((ext_vector_type(4))) float f32x4;

#define NSPLIT 64
#define NPTS   (16 * 1024 * 32)   // 524288 points
#define NCH    128

__device__ __forceinline__ short f2bf(float f) {
  unsigned u = __float_as_uint(f);
  u += 0x7fffu + ((u >> 16) & 1u);   // round-to-nearest-even bf16 (manual, proven)
  return (short)(u >> 16);
}
// HW conversion path: compiler emits v_cvt_pk_bf16_f32 for the cast (m240:
// the CAST is the fast path; hand-written cvt_pk asm was both wrong-prone
// and slower). Used in hot phase kernels only.
__device__ __forceinline__ short bfc(float f) {
  __hip_bfloat16 h = __float2bfloat16(f);
  union { __hip_bfloat16 b; short s; } u;
  u.b = h;
  return u.s;
}
__device__ __forceinline__ float bf2f(short s) {
  return __uint_as_float(((unsigned)(unsigned short)s) << 16);
}

// ---------- prep: pack weights into MFMA B-fragment order; zero stats ----------
// wp[((f*64 + l)*8 + u)] = bf16( w[o=nb*16+(l&15)][k=kb*32+(l>>4)*8+u] ), f=nb*4+kb
__global__ __launch_bounds__(256) void k_prep(const float* __restrict__ w1,
                                              const float* __restrict__ w2,
                                              short* __restrict__ wp1,
                                              short* __restrict__ wp2,
                                              float* __restrict__ gstats) {
  int idx = blockIdx.x * 256 + threadIdx.x;
  if (idx < 16384) {
    int t = idx;
    int u = t & 7, l = (t >> 3) & 63, f = t >> 9;
    int nb = f >> 2, kb = f & 3;
    int o = nb * 16 + (l & 15);
    int k = kb * 32 + ((l >> 4) << 3) + u;
    wp1[t] = f2bf(w1[o * 128 + k]);
  } else if (idx < 32768) {
    int t = idx - 16384;
    int u = t & 7, l = (t >> 3) & 63, f = t >> 9;
    int nb = f >> 2, kb = f & 3;
    int o = nb * 16 + (l & 15);
    int k = kb * 32 + ((l >> 4) << 3) + u;
    wp2[t] = f2bf(w2[o * 128 + k]);
  } else if (idx < 32768 + 4 * NSPLIT * 128) {
    gstats[idx - 32768] = 0.0f;
  }
}

// ---------- finalize: per-channel scale/shift ----------
__global__ __launch_bounds__(128) void k_finalize(const float* __restrict__ gsum,
                                                  const float* __restrict__ gsq,
                                                  const float* __restrict__ gamma,
                                                  const float* __restrict__ beta,
                                                  float* __restrict__ scale,
                                                  float* __restrict__ shift) {
  int c = threadIdx.x;
  float s = 0.f, q = 0.f;
  for (int sp = 0; sp < NSPLIT; ++sp) {
    s += gsum[sp * 128 + c];
    q += gsq[sp * 128 + c];
  }
  const float inv = 1.0f / (float)NPTS;
  float mean = s * inv;
  float var = q * inv - mean * mean;
  float rs = rsqrtf(var + 1e-5f);
  float sc = gamma[c] * rs;
  scale[c] = sc;
  shift[c] = beta[c] - mean * sc;
}

// ---------- finalize2x: bn2 scale/shift AND pack s2-baked w2 fragments ----------
__global__ __launch_bounds__(128) void k_finalize2x(
    const float* __restrict__ gsum, const float* __restrict__ gsq,
    const float* __restrict__ gamma, const float* __restrict__ beta,
    const float* __restrict__ w2, float* __restrict__ scale,
    float* __restrict__ shift, short* __restrict__ wp2s) {
  __shared__ float s2l[128];
  int c = threadIdx.x;
  float s = 0.f, q = 0.f;
  for (int sp = 0; sp < NSPLIT; ++sp) {
    s += gsum[sp * 128 + c];
    q += gsq[sp * 128 + c];
  }
  const float inv = 1.0f / (float)NPTS;
  float mean = s * inv;
  float var = q * inv - mean * mean;
  float rs = rsqrtf(var + 1e-5f);
  float sc = gamma[c] * rs;
  scale[c] = sc;
  shift[c] = beta[c] - mean * sc;
  s2l[c] = sc;
  __syncthreads();
  for (int e = c; e < 16384; e += 128) {
    int u = e & 7, l = (e >> 3) & 63, f = e >> 9;
    int nb = f >> 2, kb = f & 3;
    int o = nb * 16 + (l & 15);
    int k = kb * 32 + ((l >> 4) << 3) + u;
    wp2s[e] = f2bf(s2l[o] * w2[o * 128 + k]);
  }
}

// =======================  3-PASS PIPELINE (M-blocked)  =======================

// ---- P1: h1 = x @ w1^T; stats; write h1 (+x) as bf16 mm2-A-fragments ----
// (256,3): cap ~170 VGPR/wave -> 3 waves/SIMD; LDS 52KB x 3 blocks = 156KB fits.
template <int STOREX>
__global__ __launch_bounds__(256, 3) void k_p1(
    const float* __restrict__ x, const short* __restrict__ wp1,
    short* __restrict__ h1b, short* __restrict__ xbf,
    float* __restrict__ gstats) {
  __shared__ short lw1[16384];                      // 32 KB
  __shared__ __align__(16) short stripes[4 * 2048]; // 4 waves x 4 KB (4 row-tiles)
  __shared__ float redu[4 * 128 * 2];               // 4 KB

  const int tid = threadIdx.x;
  const int lane = tid & 63;
  const int wave = tid >> 6;
  const int l15 = lane & 15;
  const int l4 = lane >> 4;

  {
    const int4* sp = (const int4*)wp1;
    int4* dp = (int4*)lw1;
    for (int i = tid; i < 2048; i += 256) dp[i] = sp[i];
  }
  __syncthreads();

  float ssum[8], ssq[8];
#pragma unroll
  for (int nb = 0; nb < 8; ++nb) { ssum[nb] = 0.f; ssq[nb] = 0.f; }

  short* mys = stripes + wave * 2048;
  const int rgbase = (blockIdx.x * 256 + wave * 64) >> 4;

  // Phase A: A-fragments for all 4 row-tiles (fp32 -> bf16), batched loads
  short8 afr[4][4];
#pragma unroll
  for (int r = 0; r < 4; ++r) {
    const float* xrow = x + (size_t)((rgbase + r) * 16 + l15) * 128 + l4 * 8;
#pragma unroll
    for (int kb = 0; kb < 4; ++kb) {
      float4 v0 = *(const float4*)(xrow + kb * 32);
      float4 v1 = *(const float4*)(xrow + kb * 32 + 4);
      short8 a;
      a[0] = bfc(v0.x); a[1] = bfc(v0.y); a[2] = bfc(v0.z); a[3] = bfc(v0.w);
      a[4] = bfc(v1.x); a[5] = bfc(v1.y); a[6] = bfc(v1.z); a[7] = bfc(v1.w);
      afr[r][kb] = a;
      if (STOREX) {
        *(short8*)(xbf + ((size_t)((rgbase + r) * 4 + kb) * 64 + lane) * 8) = a;
      }
    }
  }

  const int rslot = (l4 ^ (l15 >> 2)) & 3;

  // Phase B: nb-outer MFMA, B-frags read once per nb, reused over 4 row-tiles
#pragma unroll
  for (int m = 0; m < 4; ++m) {       // channel chunk [m*32, m*32+32)
#pragma unroll
    for (int t = 0; t < 2; ++t) {
      const int nb = m * 2 + t;
      short8 b[4];
#pragma unroll
      for (int kb = 0; kb < 4; ++kb)
        b[kb] = *(const short8*)(lw1 + ((nb * 4 + kb) * 64 + lane) * 8);
#pragma unroll
      for (int r = 0; r < 4; ++r) {
        f32x4 acc = {0.f, 0.f, 0.f, 0.f};
#pragma unroll
        for (int kb = 0; kb < 4; ++kb)
          acc = __builtin_amdgcn_mfma_f32_16x16x32_bf16(afr[r][kb], b[kb], acc, 0, 0, 0);
#pragma unroll
        for (int j = 0; j < 4; ++j) {
          float h = acc[j];
          ssum[nb] += h;
          ssq[nb] += h * h;
          int p = l4 * 4 + j;
          int cp = t * 16 + l15;
          int slot = ((cp >> 3) ^ (p >> 2)) & 3;
          mys[r * 512 + p * 32 + slot * 8 + (cp & 7)] = bfc(h);
        }
      }
    }
    // transpose read-back + h1b store for chunk m, all 4 row-tiles
#pragma unroll
    for (int r = 0; r < 4; ++r) {
      short8 hf = *(const short8*)(mys + r * 512 + l15 * 32 + rslot * 8);
      *(short8*)(h1b + ((size_t)((rgbase + r) * 4 + m) * 64 + lane) * 8) = hf;
    }
  }

  // stats reduction
#pragma unroll
  for (int nb = 0; nb < 8; ++nb) {
    float a = ssum[nb], b = ssq[nb];
    a += __shfl_xor(a, 16, 64); a += __shfl_xor(a, 32, 64);
    b += __shfl_xor(b, 16, 64); b += __shfl_xor(b, 32, 64);
    if (l4 == 0) {
      int c = nb * 16 + l15;
      redu[(wave * 128 + c) * 2 + 0] = a;
      redu[(wave * 128 + c) * 2 + 1] = b;
    }
  }
  __syncthreads();
  if (tid < 128) {
    float s = 0.f, q = 0.f;
#pragma unroll
    for (int w = 0; w < 4; ++w) {
      s += redu[(w * 128 + tid) * 2 + 0];
      q += redu[(w * 128 + tid) * 2 + 1];
    }
    int split = blockIdx.x & (NSPLIT - 1);
    atomicAdd(&gstats[split * 128 + tid], s);
    atomicAdd(&gstats[NSPLIT * 128 + split * 128 + tid], q);
  }
}

// ---- shared Phase-A converter: h1b frags -> a1 frags (bn1 + lrelu) ----
// kb-outer: scale/shift LDS vectors load once per kb. NR rows starting at
// rgbase (register footprint scales with NR).
template <int NR>
__device__ __forceinline__ void load_a1(const short* __restrict__ h1b,
                                        const float* __restrict__ ls,
                                        int rgbase, int lane, int l4,
                                        short8 a1[NR][4]) {
#pragma unroll
  for (int kb = 0; kb < 4; ++kb) {
    const int c0 = kb * 32 + l4 * 8;
    f32x4 sa0 = *(const f32x4*)&ls[c0];
    f32x4 sa1 = *(const f32x4*)&ls[c0 + 4];
    f32x4 sb0 = *(const f32x4*)&ls[128 + c0];
    f32x4 sb1 = *(const f32x4*)&ls[128 + c0 + 4];
#pragma unroll
    for (int r = 0; r < NR; ++r) {
      short8 h = *(const short8*)(h1b + ((size_t)((rgbase + r) * 4 + kb) * 64 + lane) * 8);
      short8 a;
#pragma unroll
      for (int u = 0; u < 4; ++u) {
        float t = bf2f(h[u]) * sa0[u] + sb0[u];
        a[u] = bfc(fmaxf(t, 0.01f * t));
      }
#pragma unroll
      for (int u = 0; u < 4; ++u) {
        float t = bf2f(h[4 + u]) * sa1[u] + sb1[u];
        a[4 + u] = bfc(fmaxf(t, 0.01f * t));
      }
      a1[r][kb] = a;
    }
  }
}

// ---- P2: a1 = lrelu(bn1(h1)); h2 = a1 @ w2^T; stats of h2 ----
__global__ __launch_bounds__(256, 3) void k_p2(
    const short* __restrict__ h1b, const short* __restrict__ wp2,
    const float* __restrict__ scale1, const float* __restrict__ shift1,
    float* __restrict__ gstats) {
  __shared__ short lw2[16384];          // 32 KB
  __shared__ float ls[256];             // scale1 | shift1
  __shared__ float redu[4 * 128 * 2];   // 4 KB

  const int tid = threadIdx.x;
  const int lane = tid & 63;
  const int wave = tid >> 6;
  const int l15 = lane & 15;
  const int l4 = lane >> 4;

  {
    const int4* sp = (const int4*)wp2;
    int4* dp = (int4*)lw2;
    for (int i = tid; i < 2048; i += 256) dp[i] = sp[i];
    if (tid < 128) { ls[tid] = scale1[tid]; ls[128 + tid] = shift1[tid]; }
  }
  __syncthreads();

  float ssum[8], ssq[8];
#pragma unroll
  for (int nb = 0; nb < 8; ++nb) { ssum[nb] = 0.f; ssq[nb] = 0.f; }

  const int rgbase = blockIdx.x * 16 + wave * 4;

  short8 a1[4][4];
  load_a1<4>(h1b, ls, rgbase, lane, l4, a1);

  // Phase B: nb-outer, B-frag reuse
#pragma unroll
  for (int nb = 0; nb < 8; ++nb) {
    short8 b[4];
#pragma unroll
    for (int kb = 0; kb < 4; ++kb)
      b[kb] = *(const short8*)(lw2 + ((nb * 4 + kb) * 64 + lane) * 8);
#pragma unroll
    for (int r = 0; r < 4; ++r) {
      f32x4 acc = {0.f, 0.f, 0.f, 0.f};
#pragma unroll
      for (int kb = 0; kb < 4; ++kb)
        acc = __builtin_amdgcn_mfma_f32_16x16x32_bf16(a1[r][kb], b[kb], acc, 0, 0, 0);
#pragma unroll
      for (int j = 0; j < 4; ++j) {
        float h = acc[j];
        ssum[nb] += h;
        ssq[nb] += h * h;
      }
    }
  }

#pragma unroll
  for (int nb = 0; nb < 8; ++nb) {
    float a = ssum[nb], b = ssq[nb];
    a += __shfl_xor(a, 16, 64); a += __shfl_xor(a, 32, 64);
    b += __shfl_xor(b, 16, 64); b += __shfl_xor(b, 32, 64);
    if (l4 == 0) {
      int c = nb * 16 + l15;
      redu[(wave * 128 + c) * 2 + 0] = a;
      redu[(wave * 128 + c) * 2 + 1] = b;
    }
  }
  __syncthreads();
  if (tid < 128) {
    float s = 0.f, q = 0.f;
#pragma unroll
    for (int w = 0; w < 4; ++w) {
      s += redu[(w * 128 + tid) * 2 + 0];
      q += redu[(w * 128 + tid) * 2 + 1];
    }
    int split = blockIdx.x & (NSPLIT - 1);
    atomicAdd(&gstats[2 * NSPLIT * 128 + split * 128 + tid], s);
    atomicAdd(&gstats[3 * NSPLIT * 128 + split * 128 + tid], q);
  }
}

// ---- P3 full: y = lrelu( (s2*w2)x_a1 + x_bf + sh2 ); out = max over s ----
// r-pair restructure: process 2 row-tiles (= one bn-group of 32 rows) at a
// time -> fragment registers halve (128 -> 64), fits the (256,3) 170-VGPR cap.
__global__ __launch_bounds__(256, 3) void k_p3f(
    const short* __restrict__ h1b, const short* __restrict__ xbf,
    const short* __restrict__ wp2s,
    const float* __restrict__ scale1, const float* __restrict__ shift1,
    const float* __restrict__ shift2, float* __restrict__ out) {
  __shared__ short lw[16384];           // 32 KB (s2-baked w2 frags)
  __shared__ float lsf[384];            // scale1 | shift1 | sh2

  const int tid = threadIdx.x;
  const int lane = tid & 63;
  const int wave = tid >> 6;
  const int l15 = lane & 15;
  const int l4 = lane >> 4;

  {
    const int4* sp = (const int4*)wp2s;
    int4* dp = (int4*)lw;
    for (int i = tid; i < 2048; i += 256) dp[i] = sp[i];
    if (tid < 128) {
      lsf[tid] = scale1[tid];
      lsf[128 + tid] = shift1[tid];
      lsf[256 + tid] = shift2[tid];
    }
  }
  __syncthreads();

  // identity B-fragments (bf16 1.0 = 0x3F80); nb even hit u=l15-8*l4, odd +16
  const int he = l15 - l4 * 8;
  const int ho = l15 + 16 - l4 * 8;
  short8 idE, idO;
#pragma unroll
  for (int u = 0; u < 8; ++u) {
    idE[u] = (he == u) ? (short)0x3F80 : (short)0;
    idO[u] = (ho == u) ? (short)0x3F80 : (short)0;
  }

  const int rgbase = (blockIdx.x * 256 + wave * 64) >> 4;
  const int bn0 = (blockIdx.x * 256 + wave * 64) >> 5;

#pragma unroll
  for (int pr = 0; pr < 2; ++pr) {
    const int rg0 = rgbase + pr * 2;

    // Phase A (pair): x frags + a1 frags (bn1 + lrelu)
    short8 a1[2][4], xa[2][4];
#pragma unroll
    for (int r = 0; r < 2; ++r) {
#pragma unroll
      for (int kb = 0; kb < 4; ++kb)
        xa[r][kb] = *(const short8*)(xbf + ((size_t)((rg0 + r) * 4 + kb) * 64 + lane) * 8);
    }
    load_a1<2>(h1b, lsf, rg0, lane, l4, a1);

    float om[8];
#pragma unroll
    for (int nb = 0; nb < 8; ++nb) om[nb] = -3.4e38f;

    // Phase B (pair): nb-outer, B-frag reuse; residual via id-MFMA
#pragma unroll
    for (int nb = 0; nb < 8; ++nb) {
      short8 b[4];
#pragma unroll
      for (int kb = 0; kb < 4; ++kb)
        b[kb] = *(const short8*)(lw + ((nb * 4 + kb) * 64 + lane) * 8);
      const float sh = lsf[256 + nb * 16 + l15];
#pragma unroll
      for (int r = 0; r < 2; ++r) {
        f32x4 acc = {0.f, 0.f, 0.f, 0.f};
#pragma unroll
        for (int kb = 0; kb < 4; ++kb)
          acc = __builtin_amdgcn_mfma_f32_16x16x32_bf16(a1[r][kb], b[kb], acc, 0, 0, 0);
        acc = __builtin_amdgcn_mfma_f32_16x16x32_bf16(
            xa[r][nb >> 1], (nb & 1) ? idO : idE, acc, 0, 0, 0);
#pragma unroll
        for (int j = 0; j < 4; ++j) {
          float v = acc[j] + sh;
          v = fmaxf(v, 0.01f * v);
          om[nb] = fmaxf(om[nb], v);
        }
      }
    }

    // reduce & store this pair's bn-group
#pragma unroll
    for (int nb = 0; nb < 8; ++nb) {
      float m = om[nb];
      m = fmaxf(m, __shfl_xor(m, 16, 64));
      m = fmaxf(m, __shfl_xor(m, 32, 64));
      if (l4 == 0) out[(size_t)(bn0 + pr) * 128 + nb * 16 + l15] = m;
    }
  }
}

// ---- P3 mid-tier fallback (round-3 proven): scattered fp32 x residual ----
__global__ __launch_bounds__(256, 2) void k_p3m(
    const float* __restrict__ x, const short* __restrict__ h1b,
    const short* __restrict__ wp2,
    const float* __restrict__ scale1, const float* __restrict__ shift1,
    const float* __restrict__ scale2, const float* __restrict__ shift2,
    float* __restrict__ out) {
  __shared__ short lw2[16384];
  __shared__ float ls1[256];
  __shared__ float ls2[256];

  const int tid = threadIdx.x;
  const int lane = tid & 63;
  const int wave = tid >> 6;
  const int l15 = lane & 15;
  const int l4 = lane >> 4;

  {
    const int4* sp = (const int4*)wp2;
    int4* dp = (int4*)lw2;
    for (int i = tid; i < 2048; i += 256) dp[i] = sp[i];
    if (tid < 128) {
      ls1[tid] = scale1[tid];
      ls1[128 + tid] = shift1[tid];
      ls2[tid] = scale2[tid];
      ls2[128 + tid] = shift2[tid];
    }
  }
  __syncthreads();

  float om0[8], om1[8];
#pragma unroll
  for (int nb = 0; nb < 8; ++nb) { om0[nb] = -3.4e38f; om1[nb] = -3.4e38f; }

  const int rowblk = blockIdx.x * 256;

  for (int rt = 0; rt < 4; ++rt) {
    const int row0 = rowblk + wave * 64 + rt * 16;
    const int rg = row0 >> 4;
    short8 a1[4];
#pragma unroll
    for (int kb = 0; kb < 4; ++kb) {
      short8 h = *(const short8*)(h1b + ((size_t)(rg * 4 + kb) * 64 + lane) * 8);
      const int c0 = kb * 32 + l4 * 8;
      f32x4 sa0 = *(const f32x4*)&ls1[c0];
      f32x4 sa1 = *(const f32x4*)&ls1[c0 + 4];
      f32x4 sb0 = *(const f32x4*)&ls1[128 + c0];
      f32x4 sb1 = *(const f32x4*)&ls1[128 + c0 + 4];
      short8 a;
#pragma unroll
      for (int u = 0; u < 4; ++u) {
        float v = bf2f(h[u]) * sa0[u] + sb0[u];
        v = v > 0.f ? v : 0.01f * v;
        a[u] = f2bf(v);
      }
#pragma unroll
      for (int u = 0; u < 4; ++u) {
        float v = bf2f(h[4 + u]) * sa1[u] + sb1[u];
        v = v > 0.f ? v : 0.01f * v;
        a[4 + u] = f2bf(v);
      }
      a1[kb] = a;
    }
#pragma unroll
    for (int nb = 0; nb < 8; ++nb) {
      f32x4 acc = {0.f, 0.f, 0.f, 0.f};
#pragma unroll
      for (int kb = 0; kb < 4; ++kb) {
        short8 b = *(const short8*)(lw2 + ((nb * 4 + kb) * 64 + lane) * 8);
        acc = __builtin_amdgcn_mfma_f32_16x16x32_bf16(a1[kb], b, acc, 0, 0, 0);
      }
      const float sc = ls2[nb * 16 + l15];
      const float sh = ls2[128 + nb * 16 + l15];
#pragma unroll
      for (int j = 0; j < 4; ++j) {
        int p = l4 * 4 + j;
        float xr = x[(size_t)(row0 + p) * 128 + nb * 16 + l15];
        float v = acc[j] * sc + sh + xr;
        v = v > 0.f ? v : 0.01f * v;
        if (rt < 2) om0[nb] = fmaxf(om0[nb], v);
        else        om1[nb] = fmaxf(om1[nb], v);
      }
    }
  }

  const int bn0 = (rowblk + wave * 64) >> 5;
#pragma unroll
  for (int nb = 0; nb < 8; ++nb) {
    float m0 = om0[nb], m1 = om1[nb];
    m0 = fmaxf(m0, __shfl_xor(m0, 16, 64)); m0 = fmaxf(m0, __shfl_xor(m0, 32, 64));
    m1 = fmaxf(m1, __shfl_xor(m1, 16, 64)); m1 = fmaxf(m1, __shfl_xor(m1, 32, 64));
    int c = nb * 16 + l15;
    if (l4 == 0)      out[(size_t)bn0 * 128 + c] = m0;
    else if (l4 == 1) out[(size_t)(bn0 + 1) * 128 + c] = m1;
  }
}

// =======================  FALLBACK (round-1 proven path)  =======================
template <int PHASE>
__global__ __launch_bounds__(256, 2) void k_gemm(
    const float* __restrict__ x,
    const short* __restrict__ wp1, const short* __restrict__ wp2,
    const float* __restrict__ scale1, const float* __restrict__ shift1,
    const float* __restrict__ scale2, const float* __restrict__ shift2,
    float* __restrict__ gstats, float* __restrict__ out) {
  __shared__ short lw1[16384];
  __shared__ short lw2[(PHASE >= 2) ? 16384 : 16];
  __shared__ short stripes[(PHASE >= 2) ? 8192 : 2048];

  const int tid = threadIdx.x;
  const int lane = tid & 63;
  const int wave = tid >> 6;
  const int l15 = lane & 15;
  const int l4 = lane >> 4;

  {
    const int4* s1p = (const int4*)wp1;
    int4* d1p = (int4*)lw1;
    for (int i = tid; i < 2048; i += 256) d1p[i] = s1p[i];
    if (PHASE >= 2) {
      const int4* s2p = (const int4*)wp2;
      int4* d2p = (int4*)lw2;
      for (int i = tid; i < 2048; i += 256) d2p[i] = s2p[i];
    }
  }
  __syncthreads();

  float s1[8], sh1[8], s2[8], sh2[8];
  if (PHASE >= 2) {
#pragma unroll
    for (int nb = 0; nb < 8; ++nb) {
      s1[nb] = scale1[nb * 16 + l15];
      sh1[nb] = shift1[nb * 16 + l15];
    }
  }
  if (PHASE == 3) {
#pragma unroll
    for (int nb = 0; nb < 8; ++nb) {
      s2[nb] = scale2[nb * 16 + l15];
      sh2[nb] = shift2[nb * 16 + l15];
    }
  }

  float ssum[8], ssq[8], om0[8], om1[8];
#pragma unroll
  for (int nb = 0; nb < 8; ++nb) {
    ssum[nb] = 0.f; ssq[nb] = 0.f;
    om0[nb] = -3.4e38f; om1[nb] = -3.4e38f;
  }

  char* mystripe = (char*)(stripes) + wave * 4096;
  const int rowblk = blockIdx.x * 256;

  for (int rt = 0; rt < 4; ++rt) {
    const int row0 = rowblk + wave * 64 + rt * 16;
    short8 afr[4];
    const float* xrow = x + (size_t)(row0 + l15) * 128 + l4 * 8;
#pragma unroll
    for (int kb = 0; kb < 4; ++kb) {
      float4 v0 = *(const float4*)(xrow + kb * 32);
      float4 v1 = *(const float4*)(xrow + kb * 32 + 4);
      short8 a;
      a[0] = f2bf(v0.x); a[1] = f2bf(v0.y); a[2] = f2bf(v0.z); a[3] = f2bf(v0.w);
      a[4] = f2bf(v1.x); a[5] = f2bf(v1.y); a[6] = f2bf(v1.z); a[7] = f2bf(v1.w);
      afr[kb] = a;
    }
#pragma unroll
    for (int nb = 0; nb < 8; ++nb) {
      f32x4 acc = {0.f, 0.f, 0.f, 0.f};
#pragma unroll
      for (int kb = 0; kb < 4; ++kb) {
        short8 b = *(const short8*)(lw1 + ((nb * 4 + kb) * 64 + lane) * 8);
        acc = __builtin_amdgcn_mfma_f32_16x16x32_bf16(afr[kb], b, acc, 0, 0, 0);
      }
      if (PHASE == 1) {
#pragma unroll
        for (int j = 0; j < 4; ++j) {
          float h = acc[j];
          ssum[nb] += h;
          ssq[nb] += h * h;
        }
      } else {
#pragma unroll
        for (int j = 0; j < 4; ++j) {
          float v = acc[j] * s1[nb] + sh1[nb];
          v = v > 0.f ? v : 0.01f * v;
          int p = l4 * 4 + j;
          int cb = (nb * 16 + l15) * 2;
          int off = (p << 8) | ((((cb >> 4) ^ (p & 7)) << 4) | (cb & 15));
          *(short*)(mystripe + off) = f2bf(v);
        }
      }
    }
    if (PHASE >= 2) {
      short8 a2[4];
#pragma unroll
      for (int kb = 0; kb < 4; ++kb) {
        int chunk = (kb * 4 + l4) ^ (l15 & 7);
        int off = (l15 << 8) | (chunk << 4);
        a2[kb] = *(const short8*)(mystripe + off);
      }
#pragma unroll
      for (int nb = 0; nb < 8; ++nb) {
        f32x4 acc = {0.f, 0.f, 0.f, 0.f};
#pragma unroll
        for (int kb = 0; kb < 4; ++kb) {
          short8 b = *(const short8*)(lw2 + ((nb * 4 + kb) * 64 + lane) * 8);
          acc = __builtin_amdgcn_mfma_f32_16x16x32_bf16(a2[kb], b, acc, 0, 0, 0);
        }
        if (PHASE == 2) {
#pragma unroll
          for (int j = 0; j < 4; ++j) {
            float h = acc[j];
            ssum[nb] += h;
            ssq[nb] += h * h;
          }
        } else {
#pragma unroll
          for (int j = 0; j < 4; ++j) {
            int p = l4 * 4 + j;
            float xr = x[(size_t)(row0 + p) * 128 + nb * 16 + l15];
            float v = acc[j] * s2[nb] + sh2[nb] + xr;
            v = v > 0.f ? v : 0.01f * v;
            if (rt < 2) om0[nb] = fmaxf(om0[nb], v);
            else        om1[nb] = fmaxf(om1[nb], v);
          }
        }
      }
    }
  }

  if (PHASE <= 2) {
    __syncthreads();
    float* redu = (float*)stripes;
#pragma unroll
    for (int nb = 0; nb < 8; ++nb) {
      float a = ssum[nb], b = ssq[nb];
      a += __shfl_xor(a, 16, 64); a += __shfl_xor(a, 32, 64);
      b += __shfl_xor(b, 16, 64); b += __shfl_xor(b, 32, 64);
      if (l4 == 0) {
        int c = nb * 16 + l15;
        redu[(wave * 128 + c) * 2 + 0] = a;
        redu[(wave * 128 + c) * 2 + 1] = b;
      }
    }
    __syncthreads();
    if (tid < 128) {
      float s = 0.f, q = 0.f;
#pragma unroll
      for (int w = 0; w < 4; ++w) {
        s += redu[(w * 128 + tid) * 2 + 0];
        q += redu[(w * 128 + tid) * 2 + 1];
      }
      int split = blockIdx.x & (NSPLIT - 1);
      int base = (PHASE == 1 ? 0 : 2) * NSPLIT * 128;
      atomicAdd(&gstats[base + split * 128 + tid], s);
      atomicAdd(&gstats[base + NSPLIT * 128 + split * 128 + tid], q);
    }
  } else {
    const int bn0 = (rowblk + wave * 64) >> 5;
#pragma unroll
    for (int nb = 0; nb < 8; ++nb) {
      float m0 = om0[nb], m1 = om1[nb];
      m0 = fmaxf(m0, __shfl_xor(m0, 16, 64)); m0 = fmaxf(m0, __shfl_xor(m0, 32, 64));
      m1 = fmaxf(m1, __shfl_xor(m1, 16, 64)); m1 = fmaxf(m1, __shfl_xor(m1, 32, 64));
      int c = nb * 16 + l15;
      if (l4 == 0)      out[(size_t)bn0 * 128 + c] = m0;
      else if (l4 == 1) out[(size_t)(bn0 + 1) * 128 + c] = m1;
    }
  }
}

extern "C" void kernel_launch(void* const* d_in, const int* in_sizes, int n_in,
                              void* d_out, int out_size, void* d_ws, size_t ws_size,
                              hipStream_t stream) {
  const float* x   = (const float*)d_in[0];
  const float* w1  = (const float*)d_in[1];
  const float* g1  = (const float*)d_in[3];
  const float* be1 = (const float*)d_in[4];
  const float* w2  = (const float*)d_in[5];
  const float* g2  = (const float*)d_in[7];
  const float* be2 = (const float*)d_in[8];
  float* out = (float*)d_out;

  char* ws = (char*)d_ws;
  short* wp1  = (short*)ws;                        // 32 KB
  short* wp2  = (short*)(ws + 32768);              // 32 KB
  short* wp2s = (short*)(ws + 65536);              // 32 KB (s2-baked)
  float* gstats = (float*)(ws + 98304);            // 128 KB
  float* scale1 = (float*)(ws + 98304 + 131072);   // 512 floats: s1|sh1|s2|sh2
  float* shift1 = scale1 + 128;
  float* scale2 = scale1 + 256;
  float* shift2 = scale1 + 384;
  const size_t H1B = (size_t)NPTS * 128 * 2;       // 134,217,728 B
  short* h1b = (short*)(ws + 262144);
  short* xbf = (short*)(ws + 262144 + H1B);

  const size_t need_full = 262144 + 2 * H1B;
  const size_t need_mid  = 262144 + H1B;

  k_prep<<<256, 256, 0, stream>>>(w1, w2, wp1, wp2, gstats);

  if (ws_size >= need_full) {
    k_p1<1><<<NPTS / 256, 256, 0, stream>>>(x, wp1, h1b, xbf, gstats);
    k_finalize<<<1, 128, 0, stream>>>(gstats, gstats + NSPLIT * 128, g1, be1,
                                      scale1, shift1);
    k_p2<<<NPTS / 256, 256, 0, stream>>>(h1b, wp2, scale1, shift1, gstats);
    k_finalize2x<<<1, 128, 0, stream>>>(gstats + 2 * NSPLIT * 128,
                                        gstats + 3 * NSPLIT * 128, g2, be2,
                                        w2, scale2, shift2, wp2s);
    k_p3f<<<NPTS / 256, 256, 0, stream>>>(h1b, xbf, wp2s, scale1, shift1,
                                          shift2, out);
  } else if (ws_size >= need_mid) {
    k_p1<0><<<NPTS / 256, 256, 0, stream>>>(x, wp1, h1b, (short*)0, gstats);
    k_finalize<<<1, 128, 0, stream>>>(gstats, gstats + NSPLIT * 128, g1, be1,
                                      scale1, shift1);
    k_p2<<<NPTS / 256, 256, 0, stream>>>(h1b, wp2, scale1, shift1, gstats);
    k_finalize<<<1, 128, 0, stream>>>(gstats + 2 * NSPLIT * 128,
                                      gstats + 3 * NSPLIT * 128, g2, be2,
                                      scale2, shift2);
    k_p3m<<<NPTS / 256, 256, 0, stream>>>(x, h1b, wp2, scale1, shift1,
                                          scale2, shift2, out);
  } else {
    k_gemm<1><<<NPTS / 256, 256, 0, stream>>>(x, wp1, wp2, scale1, shift1,
                                              scale2, shift2, gstats, out);
    k_finalize<<<1, 128, 0, stream>>>(gstats, gstats + NSPLIT * 128, g1, be1,
                                      scale1, shift1);
    k_gemm<2><<<NPTS / 256, 256, 0, stream>>>(x, wp1, wp2, scale1, shift1,
                                              scale2, shift2, gstats, out);
    k_finalize<<<1, 128, 0, stream>>>(gstats + 2 * NSPLIT * 128,
                                      gstats + 3 * NSPLIT * 128, g2, be2,
                                      scale2, shift2);
    k_gemm<3><<<NPTS / 256, 256, 0, stream>>>(x, wp1, wp2, scale1, shift1,
                                              scale2, shift2, gstats, out);
  }
}

// Round 9
// 243.307 us; speedup vs baseline: 1.1966x; 1.1966x over previous
//
#include <hip/hip_runtime.h>
#include <hip/hip_bf16.h>

typedef __attribute__((ext_vector_type(8))) short short8;
typedef __attribute__((ext_vector_type(4))) float f32x4;

#define NSPLIT 64
#define NPTS   (16 * 1024 * 32)   // 524288 points
#define NCH    128

__device__ __forceinline__ short f2bf(float f) {
  unsigned u = __float_as_uint(f);
  u += 0x7fffu + ((u >> 16) & 1u);   // round-to-nearest-even bf16 (manual, proven)
  return (short)(u >> 16);
}
// HW conversion via the cast (compiler emits v_cvt_pk_bf16_f32; m240: cast is
// the fast path). Verified bit-identical to f2bf in round 8 (absmax 0.03125).
__device__ __forceinline__ short bfc(float f) {
  __hip_bfloat16 h = __float2bfloat16(f);
  union { __hip_bfloat16 b; short s; } u;
  u.b = h;
  return u.s;
}
__device__ __forceinline__ float bf2f(short s) {
  return __uint_as_float(((unsigned)(unsigned short)s) << 16);
}

// NOTE (rounds 2 & 8 post-mortem): __launch_bounds__(256, >2) halves the
// unified VGPR+AGPR budget below this code's live state and SPILLS (trace
// signature: VGPR_Count = cap/2, WRITE_SIZE +60..340 MB over ideal).
// (256,2) is the proven operating point. Do not raise occupancy via bounds.

// ---------- prep: pack weights into MFMA B-fragment order; zero stats ----------
// wp[((f*64 + l)*8 + u)] = bf16( w[o=nb*16+(l&15)][k=kb*32+(l>>4)*8+u] ), f=nb*4+kb
__global__ __launch_bounds__(256) void k_prep(const float* __restrict__ w1,
                                              const float* __restrict__ w2,
                                              short* __restrict__ wp1,
                                              short* __restrict__ wp2,
                                              float* __restrict__ gstats) {
  int idx = blockIdx.x * 256 + threadIdx.x;
  if (idx < 16384) {
    int t = idx;
    int u = t & 7, l = (t >> 3) & 63, f = t >> 9;
    int nb = f >> 2, kb = f & 3;
    int o = nb * 16 + (l & 15);
    int k = kb * 32 + ((l >> 4) << 3) + u;
    wp1[t] = f2bf(w1[o * 128 + k]);
  } else if (idx < 32768) {
    int t = idx - 16384;
    int u = t & 7, l = (t >> 3) & 63, f = t >> 9;
    int nb = f >> 2, kb = f & 3;
    int o = nb * 16 + (l & 15);
    int k = kb * 32 + ((l >> 4) << 3) + u;
    wp2[t] = f2bf(w2[o * 128 + k]);
  } else if (idx < 32768 + 4 * NSPLIT * 128) {
    gstats[idx - 32768] = 0.0f;
  }
}

// ---------- finalize: per-channel scale/shift ----------
__global__ __launch_bounds__(128) void k_finalize(const float* __restrict__ gsum,
                                                  const float* __restrict__ gsq,
                                                  const float* __restrict__ gamma,
                                                  const float* __restrict__ beta,
                                                  float* __restrict__ scale,
                                                  float* __restrict__ shift) {
  int c = threadIdx.x;
  float s = 0.f, q = 0.f;
  for (int sp = 0; sp < NSPLIT; ++sp) {
    s += gsum[sp * 128 + c];
    q += gsq[sp * 128 + c];
  }
  const float inv = 1.0f / (float)NPTS;
  float mean = s * inv;
  float var = q * inv - mean * mean;
  float rs = rsqrtf(var + 1e-5f);
  float sc = gamma[c] * rs;
  scale[c] = sc;
  shift[c] = beta[c] - mean * sc;
}

// ---------- finalize2x: bn2 scale/shift AND pack s2-baked w2 fragments ----------
__global__ __launch_bounds__(128) void k_finalize2x(
    const float* __restrict__ gsum, const float* __restrict__ gsq,
    const float* __restrict__ gamma, const float* __restrict__ beta,
    const float* __restrict__ w2, float* __restrict__ scale,
    float* __restrict__ shift, short* __restrict__ wp2s) {
  __shared__ float s2l[128];
  int c = threadIdx.x;
  float s = 0.f, q = 0.f;
  for (int sp = 0; sp < NSPLIT; ++sp) {
    s += gsum[sp * 128 + c];
    q += gsq[sp * 128 + c];
  }
  const float inv = 1.0f / (float)NPTS;
  float mean = s * inv;
  float var = q * inv - mean * mean;
  float rs = rsqrtf(var + 1e-5f);
  float sc = gamma[c] * rs;
  scale[c] = sc;
  shift[c] = beta[c] - mean * sc;
  s2l[c] = sc;
  __syncthreads();
  for (int e = c; e < 16384; e += 128) {
    int u = e & 7, l = (e >> 3) & 63, f = e >> 9;
    int nb = f >> 2, kb = f & 3;
    int o = nb * 16 + (l & 15);
    int k = kb * 32 + ((l >> 4) << 3) + u;
    wp2s[e] = f2bf(s2l[o] * w2[o * 128 + k]);
  }
}

// =======================  3-PASS PIPELINE (M-blocked)  =======================

// ---- P1: h1 = x @ w1^T; stats; write h1 (+x) as bf16 mm2-A-fragments ----
template <int STOREX>
__global__ __launch_bounds__(256, 2) void k_p1(
    const float* __restrict__ x, const short* __restrict__ wp1,
    short* __restrict__ h1b, short* __restrict__ xbf,
    float* __restrict__ gstats) {
  __shared__ short lw1[16384];                      // 32 KB
  __shared__ __align__(16) short stripes[4 * 2048]; // 4 waves x 4 KB (4 row-tiles)
  __shared__ float redu[4 * 128 * 2];               // 4 KB

  const int tid = threadIdx.x;
  const int lane = tid & 63;
  const int wave = tid >> 6;
  const int l15 = lane & 15;
  const int l4 = lane >> 4;

  {
    const int4* sp = (const int4*)wp1;
    int4* dp = (int4*)lw1;
    for (int i = tid; i < 2048; i += 256) dp[i] = sp[i];
  }
  __syncthreads();

  float ssum[8], ssq[8];
#pragma unroll
  for (int nb = 0; nb < 8; ++nb) { ssum[nb] = 0.f; ssq[nb] = 0.f; }

  short* mys = stripes + wave * 2048;
  const int rgbase = (blockIdx.x * 256 + wave * 64) >> 4;

  // Phase A: A-fragments for all 4 row-tiles (fp32 -> bf16), batched loads
  short8 afr[4][4];
#pragma unroll
  for (int r = 0; r < 4; ++r) {
    const float* xrow = x + (size_t)((rgbase + r) * 16 + l15) * 128 + l4 * 8;
#pragma unroll
    for (int kb = 0; kb < 4; ++kb) {
      float4 v0 = *(const float4*)(xrow + kb * 32);
      float4 v1 = *(const float4*)(xrow + kb * 32 + 4);
      short8 a;
      a[0] = bfc(v0.x); a[1] = bfc(v0.y); a[2] = bfc(v0.z); a[3] = bfc(v0.w);
      a[4] = bfc(v1.x); a[5] = bfc(v1.y); a[6] = bfc(v1.z); a[7] = bfc(v1.w);
      afr[r][kb] = a;
      if (STOREX) {
        *(short8*)(xbf + ((size_t)((rgbase + r) * 4 + kb) * 64 + lane) * 8) = a;
      }
    }
  }

  // Phase B: nb-outer MFMA, B-frags read once per nb, reused over 4 row-tiles
#pragma unroll
  for (int m = 0; m < 4; ++m) {       // channel chunk [m*32, m*32+32)
#pragma unroll
    for (int t = 0; t < 2; ++t) {
      const int nb = m * 2 + t;
      short8 b[4];
#pragma unroll
      for (int kb = 0; kb < 4; ++kb)
        b[kb] = *(const short8*)(lw1 + ((nb * 4 + kb) * 64 + lane) * 8);
#pragma unroll
      for (int r = 0; r < 4; ++r) {
        f32x4 acc = {0.f, 0.f, 0.f, 0.f};
#pragma unroll
        for (int kb = 0; kb < 4; ++kb)
          acc = __builtin_amdgcn_mfma_f32_16x16x32_bf16(afr[r][kb], b[kb], acc, 0, 0, 0);
#pragma unroll
        for (int j = 0; j < 4; ++j) {
          float h = acc[j];
          ssum[nb] += h;
          ssq[nb] += h * h;
          int p = l4 * 4 + j;
          int cp = t * 16 + l15;
          int slot = ((cp >> 3) ^ (p >> 2)) & 3;
          mys[r * 512 + p * 32 + slot * 8 + (cp & 7)] = bfc(h);
        }
      }
    }
    // transpose read-back + h1b store for chunk m, all 4 row-tiles
#pragma unroll
    for (int r = 0; r < 4; ++r) {
      int rslot = (l4 ^ (l15 >> 2)) & 3;
      short8 hf = *(const short8*)(mys + r * 512 + l15 * 32 + rslot * 8);
      *(short8*)(h1b + ((size_t)((rgbase + r) * 4 + m) * 64 + lane) * 8) = hf;
    }
  }

  // stats reduction
#pragma unroll
  for (int nb = 0; nb < 8; ++nb) {
    float a = ssum[nb], b = ssq[nb];
    a += __shfl_xor(a, 16, 64); a += __shfl_xor(a, 32, 64);
    b += __shfl_xor(b, 16, 64); b += __shfl_xor(b, 32, 64);
    if (l4 == 0) {
      int c = nb * 16 + l15;
      redu[(wave * 128 + c) * 2 + 0] = a;
      redu[(wave * 128 + c) * 2 + 1] = b;
    }
  }
  __syncthreads();
  if (tid < 128) {
    float s = 0.f, q = 0.f;
#pragma unroll
    for (int w = 0; w < 4; ++w) {
      s += redu[(w * 128 + tid) * 2 + 0];
      q += redu[(w * 128 + tid) * 2 + 1];
    }
    int split = blockIdx.x & (NSPLIT - 1);
    atomicAdd(&gstats[split * 128 + tid], s);
    atomicAdd(&gstats[NSPLIT * 128 + split * 128 + tid], q);
  }
}

// ---- shared Phase-A converter: h1b frags -> a1 frags (bn1 + lrelu) ----
// kb-outer: scale/shift LDS vectors load once per kb (16 ds_read_b128/wave).
__device__ __forceinline__ void load_a1(const short* __restrict__ h1b,
                                        const float* __restrict__ ls,
                                        int rgbase, int lane, int l4,
                                        short8 a1[4][4]) {
#pragma unroll
  for (int kb = 0; kb < 4; ++kb) {
    const int c0 = kb * 32 + l4 * 8;
    f32x4 sa0 = *(const f32x4*)&ls[c0];
    f32x4 sa1 = *(const f32x4*)&ls[c0 + 4];
    f32x4 sb0 = *(const f32x4*)&ls[128 + c0];
    f32x4 sb1 = *(const f32x4*)&ls[128 + c0 + 4];
#pragma unroll
    for (int r = 0; r < 4; ++r) {
      short8 h = *(const short8*)(h1b + ((size_t)((rgbase + r) * 4 + kb) * 64 + lane) * 8);
      short8 a;
#pragma unroll
      for (int u = 0; u < 4; ++u) {
        float t = bf2f(h[u]) * sa0[u] + sb0[u];
        a[u] = bfc(fmaxf(t, 0.01f * t));
      }
#pragma unroll
      for (int u = 0; u < 4; ++u) {
        float t = bf2f(h[4 + u]) * sa1[u] + sb1[u];
        a[4 + u] = bfc(fmaxf(t, 0.01f * t));
      }
      a1[r][kb] = a;
    }
  }
}

// ---- P2: a1 = lrelu(bn1(h1)); h2 = a1 @ w2^T; stats of h2 ----
__global__ __launch_bounds__(256, 2) void k_p2(
    const short* __restrict__ h1b, const short* __restrict__ wp2,
    const float* __restrict__ scale1, const float* __restrict__ shift1,
    float* __restrict__ gstats) {
  __shared__ short lw2[16384];          // 32 KB
  __shared__ float ls[256];             // scale1 | shift1
  __shared__ float redu[4 * 128 * 2];   // 4 KB

  const int tid = threadIdx.x;
  const int lane = tid & 63;
  const int wave = tid >> 6;
  const int l15 = lane & 15;
  const int l4 = lane >> 4;

  {
    const int4* sp = (const int4*)wp2;
    int4* dp = (int4*)lw2;
    for (int i = tid; i < 2048; i += 256) dp[i] = sp[i];
    if (tid < 128) { ls[tid] = scale1[tid]; ls[128 + tid] = shift1[tid]; }
  }
  __syncthreads();

  float ssum[8], ssq[8];
#pragma unroll
  for (int nb = 0; nb < 8; ++nb) { ssum[nb] = 0.f; ssq[nb] = 0.f; }

  const int rgbase = blockIdx.x * 16 + wave * 4;

  short8 a1[4][4];
  load_a1(h1b, ls, rgbase, lane, l4, a1);

  // Phase B: nb-outer, B-frag reuse
#pragma unroll
  for (int nb = 0; nb < 8; ++nb) {
    short8 b[4];
#pragma unroll
    for (int kb = 0; kb < 4; ++kb)
      b[kb] = *(const short8*)(lw2 + ((nb * 4 + kb) * 64 + lane) * 8);
#pragma unroll
    for (int r = 0; r < 4; ++r) {
      f32x4 acc = {0.f, 0.f, 0.f, 0.f};
#pragma unroll
      for (int kb = 0; kb < 4; ++kb)
        acc = __builtin_amdgcn_mfma_f32_16x16x32_bf16(a1[r][kb], b[kb], acc, 0, 0, 0);
#pragma unroll
      for (int j = 0; j < 4; ++j) {
        float h = acc[j];
        ssum[nb] += h;
        ssq[nb] += h * h;
      }
    }
  }

#pragma unroll
  for (int nb = 0; nb < 8; ++nb) {
    float a = ssum[nb], b = ssq[nb];
    a += __shfl_xor(a, 16, 64); a += __shfl_xor(a, 32, 64);
    b += __shfl_xor(b, 16, 64); b += __shfl_xor(b, 32, 64);
    if (l4 == 0) {
      int c = nb * 16 + l15;
      redu[(wave * 128 + c) * 2 + 0] = a;
      redu[(wave * 128 + c) * 2 + 1] = b;
    }
  }
  __syncthreads();
  if (tid < 128) {
    float s = 0.f, q = 0.f;
#pragma unroll
    for (int w = 0; w < 4; ++w) {
      s += redu[(w * 128 + tid) * 2 + 0];
      q += redu[(w * 128 + tid) * 2 + 1];
    }
    int split = blockIdx.x & (NSPLIT - 1);
    atomicAdd(&gstats[2 * NSPLIT * 128 + split * 128 + tid], s);
    atomicAdd(&gstats[3 * NSPLIT * 128 + split * 128 + tid], q);
  }
}

// ---- P3 full: y = lrelu( (s2*w2)x_a1 + x_bf + sh2 ); out = max over s ----
__global__ __launch_bounds__(256, 2) void k_p3f(
    const short* __restrict__ h1b, const short* __restrict__ xbf,
    const short* __restrict__ wp2s,
    const float* __restrict__ scale1, const float* __restrict__ shift1,
    const float* __restrict__ shift2, float* __restrict__ out) {
  __shared__ short lw[16384];           // 32 KB (s2-baked w2 frags)
  __shared__ float lsf[384];            // scale1 | shift1 | sh2

  const int tid = threadIdx.x;
  const int lane = tid & 63;
  const int wave = tid >> 6;
  const int l15 = lane & 15;
  const int l4 = lane >> 4;

  {
    const int4* sp = (const int4*)wp2s;
    int4* dp = (int4*)lw;
    for (int i = tid; i < 2048; i += 256) dp[i] = sp[i];
    if (tid < 128) {
      lsf[tid] = scale1[tid];
      lsf[128 + tid] = shift1[tid];
      lsf[256 + tid] = shift2[tid];
    }
  }
  __syncthreads();

  // identity B-fragments (bf16 1.0 = 0x3F80); nb even hit u=l15-8*l4, odd +16
  const int he = l15 - l4 * 8;
  const int ho = l15 + 16 - l4 * 8;
  short8 idE, idO;
#pragma unroll
  for (int u = 0; u < 8; ++u) {
    idE[u] = (he == u) ? (short)0x3F80 : (short)0;
    idO[u] = (ho == u) ? (short)0x3F80 : (short)0;
  }

  const int rgbase = (blockIdx.x * 256 + wave * 64) >> 4;

  // Phase A: x frags + a1 frags (bn1 + lrelu)
  short8 a1[4][4], xa[4][4];
#pragma unroll
  for (int r = 0; r < 4; ++r) {
#pragma unroll
    for (int kb = 0; kb < 4; ++kb)
      xa[r][kb] = *(const short8*)(xbf + ((size_t)((rgbase + r) * 4 + kb) * 64 + lane) * 8);
  }
  load_a1(h1b, lsf, rgbase, lane, l4, a1);

  float om0[8], om1[8];
#pragma unroll
  for (int nb = 0; nb < 8; ++nb) { om0[nb] = -3.4e38f; om1[nb] = -3.4e38f; }

  // Phase B: nb-outer, B-frag reuse across 4 row-tiles; residual via id-MFMA
#pragma unroll
  for (int nb = 0; nb < 8; ++nb) {
    short8 b[4];
#pragma unroll
    for (int kb = 0; kb < 4; ++kb)
      b[kb] = *(const short8*)(lw + ((nb * 4 + kb) * 64 + lane) * 8);
    const float sh = lsf[256 + nb * 16 + l15];
#pragma unroll
    for (int r = 0; r < 4; ++r) {
      f32x4 acc = {0.f, 0.f, 0.f, 0.f};
#pragma unroll
      for (int kb = 0; kb < 4; ++kb)
        acc = __builtin_amdgcn_mfma_f32_16x16x32_bf16(a1[r][kb], b[kb], acc, 0, 0, 0);
      acc = __builtin_amdgcn_mfma_f32_16x16x32_bf16(
          xa[r][nb >> 1], (nb & 1) ? idO : idE, acc, 0, 0, 0);
#pragma unroll
      for (int j = 0; j < 4; ++j) {
        float v = acc[j] + sh;
        v = fmaxf(v, 0.01f * v);
        if (r < 2) om0[nb] = fmaxf(om0[nb], v);
        else       om1[nb] = fmaxf(om1[nb], v);
      }
    }
  }

  const int bn0 = (blockIdx.x * 256 + wave * 64) >> 5;
#pragma unroll
  for (int nb = 0; nb < 8; ++nb) {
    float m0 = om0[nb], m1 = om1[nb];
    m0 = fmaxf(m0, __shfl_xor(m0, 16, 64)); m0 = fmaxf(m0, __shfl_xor(m0, 32, 64));
    m1 = fmaxf(m1, __shfl_xor(m1, 16, 64)); m1 = fmaxf(m1, __shfl_xor(m1, 32, 64));
    int c = nb * 16 + l15;
    if (l4 == 0)      out[(size_t)bn0 * 128 + c] = m0;
    else if (l4 == 1) out[(size_t)(bn0 + 1) * 128 + c] = m1;
  }
}

// ---- P3 mid-tier fallback (round-3 proven): scattered fp32 x residual ----
__global__ __launch_bounds__(256, 2) void k_p3m(
    const float* __restrict__ x, const short* __restrict__ h1b,
    const short* __restrict__ wp2,
    const float* __restrict__ scale1, const float* __restrict__ shift1,
    const float* __restrict__ scale2, const float* __restrict__ shift2,
    float* __restrict__ out) {
  __shared__ short lw2[16384];
  __shared__ float ls1[256];
  __shared__ float ls2[256];

  const int tid = threadIdx.x;
  const int lane = tid & 63;
  const int wave = tid >> 6;
  const int l15 = lane & 15;
  const int l4 = lane >> 4;

  {
    const int4* sp = (const int4*)wp2;
    int4* dp = (int4*)lw2;
    for (int i = tid; i < 2048; i += 256) dp[i] = sp[i];
    if (tid < 128) {
      ls1[tid] = scale1[tid];
      ls1[128 + tid] = shift1[tid];
      ls2[tid] = scale2[tid];
      ls2[128 + tid] = shift2[tid];
    }
  }
  __syncthreads();

  float om0[8], om1[8];
#pragma unroll
  for (int nb = 0; nb < 8; ++nb) { om0[nb] = -3.4e38f; om1[nb] = -3.4e38f; }

  const int rowblk = blockIdx.x * 256;

  for (int rt = 0; rt < 4; ++rt) {
    const int row0 = rowblk + wave * 64 + rt * 16;
    const int rg = row0 >> 4;
    short8 a1[4];
#pragma unroll
    for (int kb = 0; kb < 4; ++kb) {
      short8 h = *(const short8*)(h1b + ((size_t)(rg * 4 + kb) * 64 + lane) * 8);
      const int c0 = kb * 32 + l4 * 8;
      f32x4 sa0 = *(const f32x4*)&ls1[c0];
      f32x4 sa1 = *(const f32x4*)&ls1[c0 + 4];
      f32x4 sb0 = *(const f32x4*)&ls1[128 + c0];
      f32x4 sb1 = *(const f32x4*)&ls1[128 + c0 + 4];
      short8 a;
#pragma unroll
      for (int u = 0; u < 4; ++u) {
        float v = bf2f(h[u]) * sa0[u] + sb0[u];
        v = v > 0.f ? v : 0.01f * v;
        a[u] = f2bf(v);
      }
#pragma unroll
      for (int u = 0; u < 4; ++u) {
        float v = bf2f(h[4 + u]) * sa1[u] + sb1[u];
        v = v > 0.f ? v : 0.01f * v;
        a[4 + u] = f2bf(v);
      }
      a1[kb] = a;
    }
#pragma unroll
    for (int nb = 0; nb < 8; ++nb) {
      f32x4 acc = {0.f, 0.f, 0.f, 0.f};
#pragma unroll
      for (int kb = 0; kb < 4; ++kb) {
        short8 b = *(const short8*)(lw2 + ((nb * 4 + kb) * 64 + lane) * 8);
        acc = __builtin_amdgcn_mfma_f32_16x16x32_bf16(a1[kb], b, acc, 0, 0, 0);
      }
      const float sc = ls2[nb * 16 + l15];
      const float sh = ls2[128 + nb * 16 + l15];
#pragma unroll
      for (int j = 0; j < 4; ++j) {
        int p = l4 * 4 + j;
        float xr = x[(size_t)(row0 + p) * 128 + nb * 16 + l15];
        float v = acc[j] * sc + sh + xr;
        v = v > 0.f ? v : 0.01f * v;
        if (rt < 2) om0[nb] = fmaxf(om0[nb], v);
        else        om1[nb] = fmaxf(om1[nb], v);
      }
    }
  }

  const int bn0 = (rowblk + wave * 64) >> 5;
#pragma unroll
  for (int nb = 0; nb < 8; ++nb) {
    float m0 = om0[nb], m1 = om1[nb];
    m0 = fmaxf(m0, __shfl_xor(m0, 16, 64)); m0 = fmaxf(m0, __shfl_xor(m0, 32, 64));
    m1 = fmaxf(m1, __shfl_xor(m1, 16, 64)); m1 = fmaxf(m1, __shfl_xor(m1, 32, 64));
    int c = nb * 16 + l15;
    if (l4 == 0)      out[(size_t)bn0 * 128 + c] = m0;
    else if (l4 == 1) out[(size_t)(bn0 + 1) * 128 + c] = m1;
  }
}

// =======================  FALLBACK (round-1 proven path)  =======================
template <int PHASE>
__global__ __launch_bounds__(256, 2) void k_gemm(
    const float* __restrict__ x,
    const short* __restrict__ wp1, const short* __restrict__ wp2,
    const float* __restrict__ scale1, const float* __restrict__ shift1,
    const float* __restrict__ scale2, const float* __restrict__ shift2,
    float* __restrict__ gstats, float* __restrict__ out) {
  __shared__ short lw1[16384];
  __shared__ short lw2[(PHASE >= 2) ? 16384 : 16];
  __shared__ short stripes[(PHASE >= 2) ? 8192 : 2048];

  const int tid = threadIdx.x;
  const int lane = tid & 63;
  const int wave = tid >> 6;
  const int l15 = lane & 15;
  const int l4 = lane >> 4;

  {
    const int4* s1p = (const int4*)wp1;
    int4* d1p = (int4*)lw1;
    for (int i = tid; i < 2048; i += 256) d1p[i] = s1p[i];
    if (PHASE >= 2) {
      const int4* s2p = (const int4*)wp2;
      int4* d2p = (int4*)lw2;
      for (int i = tid; i < 2048; i += 256) d2p[i] = s2p[i];
    }
  }
  __syncthreads();

  float s1[8], sh1[8], s2[8], sh2[8];
  if (PHASE >= 2) {
#pragma unroll
    for (int nb = 0; nb < 8; ++nb) {
      s1[nb] = scale1[nb * 16 + l15];
      sh1[nb] = shift1[nb * 16 + l15];
    }
  }
  if (PHASE == 3) {
#pragma unroll
    for (int nb = 0; nb < 8; ++nb) {
      s2[nb] = scale2[nb * 16 + l15];
      sh2[nb] = shift2[nb * 16 + l15];
    }
  }

  float ssum[8], ssq[8], om0[8], om1[8];
#pragma unroll
  for (int nb = 0; nb < 8; ++nb) {
    ssum[nb] = 0.f; ssq[nb] = 0.f;
    om0[nb] = -3.4e38f; om1[nb] = -3.4e38f;
  }

  char* mystripe = (char*)(stripes) + wave * 4096;
  const int rowblk = blockIdx.x * 256;

  for (int rt = 0; rt < 4; ++rt) {
    const int row0 = rowblk + wave * 64 + rt * 16;
    short8 afr[4];
    const float* xrow = x + (size_t)(row0 + l15) * 128 + l4 * 8;
#pragma unroll
    for (int kb = 0; kb < 4; ++kb) {
      float4 v0 = *(const float4*)(xrow + kb * 32);
      float4 v1 = *(const float4*)(xrow + kb * 32 + 4);
      short8 a;
      a[0] = f2bf(v0.x); a[1] = f2bf(v0.y); a[2] = f2bf(v0.z); a[3] = f2bf(v0.w);
      a[4] = f2bf(v1.x); a[5] = f2bf(v1.y); a[6] = f2bf(v1.z); a[7] = f2bf(v1.w);
      afr[kb] = a;
    }
#pragma unroll
    for (int nb = 0; nb < 8; ++nb) {
      f32x4 acc = {0.f, 0.f, 0.f, 0.f};
#pragma unroll
      for (int kb = 0; kb < 4; ++kb) {
        short8 b = *(const short8*)(lw1 + ((nb * 4 + kb) * 64 + lane) * 8);
        acc = __builtin_amdgcn_mfma_f32_16x16x32_bf16(afr[kb], b, acc, 0, 0, 0);
      }
      if (PHASE == 1) {
#pragma unroll
        for (int j = 0; j < 4; ++j) {
          float h = acc[j];
          ssum[nb] += h;
          ssq[nb] += h * h;
        }
      } else {
#pragma unroll
        for (int j = 0; j < 4; ++j) {
          float v = acc[j] * s1[nb] + sh1[nb];
          v = v > 0.f ? v : 0.01f * v;
          int p = l4 * 4 + j;
          int cb = (nb * 16 + l15) * 2;
          int off = (p << 8) | ((((cb >> 4) ^ (p & 7)) << 4) | (cb & 15));
          *(short*)(mystripe + off) = f2bf(v);
        }
      }
    }
    if (PHASE >= 2) {
      short8 a2[4];
#pragma unroll
      for (int kb = 0; kb < 4; ++kb) {
        int chunk = (kb * 4 + l4) ^ (l15 & 7);
        int off = (l15 << 8) | (chunk << 4);
        a2[kb] = *(const short8*)(mystripe + off);
      }
#pragma unroll
      for (int nb = 0; nb < 8; ++nb) {
        f32x4 acc = {0.f, 0.f, 0.f, 0.f};
#pragma unroll
        for (int kb = 0; kb < 4; ++kb) {
          short8 b = *(const short8*)(lw2 + ((nb * 4 + kb) * 64 + lane) * 8);
          acc = __builtin_amdgcn_mfma_f32_16x16x32_bf16(a2[kb], b, acc, 0, 0, 0);
        }
        if (PHASE == 2) {
#pragma unroll
          for (int j = 0; j < 4; ++j) {
            float h = acc[j];
            ssum[nb] += h;
            ssq[nb] += h * h;
          }
        } else {
#pragma unroll
          for (int j = 0; j < 4; ++j) {
            int p = l4 * 4 + j;
            float xr = x[(size_t)(row0 + p) * 128 + nb * 16 + l15];
            float v = acc[j] * s2[nb] + sh2[nb] + xr;
            v = v > 0.f ? v : 0.01f * v;
            if (rt < 2) om0[nb] = fmaxf(om0[nb], v);
            else        om1[nb] = fmaxf(om1[nb], v);
          }
        }
      }
    }
  }

  if (PHASE <= 2) {
    __syncthreads();
    float* redu = (float*)stripes;
#pragma unroll
    for (int nb = 0; nb < 8; ++nb) {
      float a = ssum[nb], b = ssq[nb];
      a += __shfl_xor(a, 16, 64); a += __shfl_xor(a, 32, 64);
      b += __shfl_xor(b, 16, 64); b += __shfl_xor(b, 32, 64);
      if (l4 == 0) {
        int c = nb * 16 + l15;
        redu[(wave * 128 + c) * 2 + 0] = a;
        redu[(wave * 128 + c) * 2 + 1] = b;
      }
    }
    __syncthreads();
    if (tid < 128) {
      float s = 0.f, q = 0.f;
#pragma unroll
      for (int w = 0; w < 4; ++w) {
        s += redu[(w * 128 + tid) * 2 + 0];
        q += redu[(w * 128 + tid) * 2 + 1];
      }
      int split = blockIdx.x & (NSPLIT - 1);
      int base = (PHASE == 1 ? 0 : 2) * NSPLIT * 128;
      atomicAdd(&gstats[base + split * 128 + tid], s);
      atomicAdd(&gstats[base + NSPLIT * 128 + split * 128 + tid], q);
    }
  } else {
    const int bn0 = (rowblk + wave * 64) >> 5;
#pragma unroll
    for (int nb = 0; nb < 8; ++nb) {
      float m0 = om0[nb], m1 = om1[nb];
      m0 = fmaxf(m0, __shfl_xor(m0, 16, 64)); m0 = fmaxf(m0, __shfl_xor(m0, 32, 64));
      m1 = fmaxf(m1, __shfl_xor(m1, 16, 64)); m1 = fmaxf(m1, __shfl_xor(m1, 32, 64));
      int c = nb * 16 + l15;
      if (l4 == 0)      out[(size_t)bn0 * 128 + c] = m0;
      else if (l4 == 1) out[(size_t)(bn0 + 1) * 128 + c] = m1;
    }
  }
}

extern "C" void kernel_launch(void* const* d_in, const int* in_sizes, int n_in,
                              void* d_out, int out_size, void* d_ws, size_t ws_size,
                              hipStream_t stream) {
  const float* x   = (const float*)d_in[0];
  const float* w1  = (const float*)d_in[1];
  const float* g1  = (const float*)d_in[3];
  const float* be1 = (const float*)d_in[4];
  const float* w2  = (const float*)d_in[5];
  const float* g2  = (const float*)d_in[7];
  const float* be2 = (const float*)d_in[8];
  float* out = (float*)d_out;

  char* ws = (char*)d_ws;
  short* wp1  = (short*)ws;                        // 32 KB
  short* wp2  = (short*)(ws + 32768);              // 32 KB
  short* wp2s = (short*)(ws + 65536);              // 32 KB (s2-baked)
  float* gstats = (float*)(ws + 98304);            // 128 KB
  float* scale1 = (float*)(ws + 98304 + 131072);   // 512 floats: s1|sh1|s2|sh2
  float* shift1 = scale1 + 128;
  float* scale2 = scale1 + 256;
  float* shift2 = scale1 + 384;
  const size_t H1B = (size_t)NPTS * 128 * 2;       // 134,217,728 B
  short* h1b = (short*)(ws + 262144);
  short* xbf = (short*)(ws + 262144 + H1B);

  const size_t need_full = 262144 + 2 * H1B;
  const size_t need_mid  = 262144 + H1B;

  k_prep<<<256, 256, 0, stream>>>(w1, w2, wp1, wp2, gstats);

  if (ws_size >= need_full) {
    k_p1<1><<<NPTS / 256, 256, 0, stream>>>(x, wp1, h1b, xbf, gstats);
    k_finalize<<<1, 128, 0, stream>>>(gstats, gstats + NSPLIT * 128, g1, be1,
                                      scale1, shift1);
    k_p2<<<NPTS / 256, 256, 0, stream>>>(h1b, wp2, scale1, shift1, gstats);
    k_finalize2x<<<1, 128, 0, stream>>>(gstats + 2 * NSPLIT * 128,
                                        gstats + 3 * NSPLIT * 128, g2, be2,
                                        w2, scale2, shift2, wp2s);
    k_p3f<<<NPTS / 256, 256, 0, stream>>>(h1b, xbf, wp2s, scale1, shift1,
                                          shift2, out);
  } else if (ws_size >= need_mid) {
    k_p1<0><<<NPTS / 256, 256, 0, stream>>>(x, wp1, h1b, (short*)0, gstats);
    k_finalize<<<1, 128, 0, stream>>>(gstats, gstats + NSPLIT * 128, g1, be1,
                                      scale1, shift1);
    k_p2<<<NPTS / 256, 256, 0, stream>>>(h1b, wp2, scale1, shift1, gstats);
    k_finalize<<<1, 128, 0, stream>>>(gstats + 2 * NSPLIT * 128,
                                      gstats + 3 * NSPLIT * 128, g2, be2,
                                      scale2, shift2);
    k_p3m<<<NPTS / 256, 256, 0, stream>>>(x, h1b, wp2, scale1, shift1,
                                          scale2, shift2, out);
  } else {
    k_gemm<1><<<NPTS / 256, 256, 0, stream>>>(x, wp1, wp2, scale1, shift1,
                                              scale2, shift2, gstats, out);
    k_finalize<<<1, 128, 0, stream>>>(gstats, gstats + NSPLIT * 128, g1, be1,
                                      scale1, shift1);
    k_gemm<2><<<NPTS / 256, 256, 0, stream>>>(x, wp1, wp2, scale1, shift1,
                                              scale2, shift2, gstats, out);
    k_finalize<<<1, 128, 0, stream>>>(gstats + 2 * NSPLIT * 128,
                                      gstats + 3 * NSPLIT * 128, g2, be2,
                                      scale2, shift2);
    k_gemm<3><<<NPTS / 256, 256, 0, stream>>>(x, wp1, wp2, scale1, shift1,
                                              scale2, shift2, gstats, out);
  }
}

// Round 10
// 240.568 us; speedup vs baseline: 1.2102x; 1.0114x over previous
//
#include <hip/hip_runtime.h>
#include <hip/hip_bf16.h>

typedef __attribute__((ext_vector_type(8))) short short8;
typedef __attribute__((ext_vector_type(4))) float f32x4;

#define NSPLIT 64
#define NPTS   (16 * 1024 * 32)   // 524288 points
#define NCH    128

__device__ __forceinline__ short f2bf(float f) {
  unsigned u = __float_as_uint(f);
  u += 0x7fffu + ((u >> 16) & 1u);   // round-to-nearest-even bf16 (manual, proven)
  return (short)(u >> 16);
}
// HW conversion via the cast (neutral perf vs f2bf, round 9; bit-identical).
__device__ __forceinline__ short bfc(float f) {
  __hip_bfloat16 h = __float2bfloat16(f);
  union { __hip_bfloat16 b; short s; } u;
  u.b = h;
  return u.s;
}
__device__ __forceinline__ float bf2f(short s) {
  return __uint_as_float(((unsigned)(unsigned short)s) << 16);
}

// NOTE (rounds 2 & 8): __launch_bounds__(256, >2) halves the unified
// VGPR+AGPR budget below live state and SPILLS (signature: VGPR_Count=cap/2,
// WRITE_SIZE ballooned). (256,2) is the operating point; occupancy is raised
// by SHRINKING state (row-pair batching), never by tightening bounds.

// ---------- prep: pack weights into MFMA B-fragment order; zero stats ----------
__global__ __launch_bounds__(256) void k_prep(const float* __restrict__ w1,
                                              const float* __restrict__ w2,
                                              short* __restrict__ wp1,
                                              short* __restrict__ wp2,
                                              float* __restrict__ gstats) {
  int idx = blockIdx.x * 256 + threadIdx.x;
  if (idx < 16384) {
    int t = idx;
    int u = t & 7, l = (t >> 3) & 63, f = t >> 9;
    int nb = f >> 2, kb = f & 3;
    int o = nb * 16 + (l & 15);
    int k = kb * 32 + ((l >> 4) << 3) + u;
    wp1[t] = f2bf(w1[o * 128 + k]);
  } else if (idx < 32768) {
    int t = idx - 16384;
    int u = t & 7, l = (t >> 3) & 63, f = t >> 9;
    int nb = f >> 2, kb = f & 3;
    int o = nb * 16 + (l & 15);
    int k = kb * 32 + ((l >> 4) << 3) + u;
    wp2[t] = f2bf(w2[o * 128 + k]);
  } else if (idx < 32768 + 4 * NSPLIT * 128) {
    gstats[idx - 32768] = 0.0f;
  }
}

// ---------- finalize: per-channel scale/shift ----------
__global__ __launch_bounds__(128) void k_finalize(const float* __restrict__ gsum,
                                                  const float* __restrict__ gsq,
                                                  const float* __restrict__ gamma,
                                                  const float* __restrict__ beta,
                                                  float* __restrict__ scale,
                                                  float* __restrict__ shift) {
  int c = threadIdx.x;
  float s = 0.f, q = 0.f;
  for (int sp = 0; sp < NSPLIT; ++sp) {
    s += gsum[sp * 128 + c];
    q += gsq[sp * 128 + c];
  }
  const float inv = 1.0f / (float)NPTS;
  float mean = s * inv;
  float var = q * inv - mean * mean;
  float rs = rsqrtf(var + 1e-5f);
  float sc = gamma[c] * rs;
  scale[c] = sc;
  shift[c] = beta[c] - mean * sc;
}

// ---------- finalize2x: bn2 scale/shift AND pack s2-baked w2 fragments ----------
__global__ __launch_bounds__(128) void k_finalize2x(
    const float* __restrict__ gsum, const float* __restrict__ gsq,
    const float* __restrict__ gamma, const float* __restrict__ beta,
    const float* __restrict__ w2, float* __restrict__ scale,
    float* __restrict__ shift, short* __restrict__ wp2s) {
  __shared__ float s2l[128];
  int c = threadIdx.x;
  float s = 0.f, q = 0.f;
  for (int sp = 0; sp < NSPLIT; ++sp) {
    s += gsum[sp * 128 + c];
    q += gsq[sp * 128 + c];
  }
  const float inv = 1.0f / (float)NPTS;
  float mean = s * inv;
  float var = q * inv - mean * mean;
  float rs = rsqrtf(var + 1e-5f);
  float sc = gamma[c] * rs;
  scale[c] = sc;
  shift[c] = beta[c] - mean * sc;
  s2l[c] = sc;
  __syncthreads();
  for (int e = c; e < 16384; e += 128) {
    int u = e & 7, l = (e >> 3) & 63, f = e >> 9;
    int nb = f >> 2, kb = f & 3;
    int o = nb * 16 + (l & 15);
    int k = kb * 32 + ((l >> 4) << 3) + u;
    wp2s[e] = f2bf(s2l[o] * w2[o * 128 + k]);
  }
}

// ==========  3-PASS PIPELINE (row-pair batching: small reg state)  ==========

// ---- P1: h1 = x @ w1^T; stats; write h1 (+x) as bf16 mm2-A-fragments ----
// Row-pair: 2 row-tiles per batch, 2 batches. afr 64->32 VGPR, stripes 16->8KB.
template <int STOREX>
__global__ __launch_bounds__(256, 2) void k_p1(
    const float* __restrict__ x, const short* __restrict__ wp1,
    short* __restrict__ h1b, short* __restrict__ xbf,
    float* __restrict__ gstats) {
  __shared__ short lw1[16384];                      // 32 KB
  __shared__ __align__(16) short stripes[4 * 1024]; // 4 waves x 2 KB (2 row-tiles)
  __shared__ float redu[4 * 128 * 2];               // 4 KB   (total ~45 KB)

  const int tid = threadIdx.x;
  const int lane = tid & 63;
  const int wave = tid >> 6;
  const int l15 = lane & 15;
  const int l4 = lane >> 4;

  {
    const int4* sp = (const int4*)wp1;
    int4* dp = (int4*)lw1;
    for (int i = tid; i < 2048; i += 256) dp[i] = sp[i];
  }
  __syncthreads();

  float ssum[8], ssq[8];
#pragma unroll
  for (int nb = 0; nb < 8; ++nb) { ssum[nb] = 0.f; ssq[nb] = 0.f; }

  short* mys = stripes + wave * 1024;
  const int rgbase = (blockIdx.x * 256 + wave * 64) >> 4;
  const int rslot = (l4 ^ (l15 >> 2)) & 3;

#pragma unroll
  for (int bt = 0; bt < 2; ++bt) {
    const int rg0 = rgbase + bt * 2;

    // Phase A (pair): A-fragments for 2 row-tiles (fp32 -> bf16)
    short8 afr[2][4];
#pragma unroll
    for (int r = 0; r < 2; ++r) {
      const float* xrow = x + (size_t)((rg0 + r) * 16 + l15) * 128 + l4 * 8;
#pragma unroll
      for (int kb = 0; kb < 4; ++kb) {
        float4 v0 = *(const float4*)(xrow + kb * 32);
        float4 v1 = *(const float4*)(xrow + kb * 32 + 4);
        short8 a;
        a[0] = bfc(v0.x); a[1] = bfc(v0.y); a[2] = bfc(v0.z); a[3] = bfc(v0.w);
        a[4] = bfc(v1.x); a[5] = bfc(v1.y); a[6] = bfc(v1.z); a[7] = bfc(v1.w);
        afr[r][kb] = a;
        if (STOREX) {
          *(short8*)(xbf + ((size_t)((rg0 + r) * 4 + kb) * 64 + lane) * 8) = a;
        }
      }
    }

    // Phase B (pair): nb-outer MFMA, B-frags reused over the 2 row-tiles
#pragma unroll
    for (int m = 0; m < 4; ++m) {       // channel chunk [m*32, m*32+32)
#pragma unroll
      for (int t = 0; t < 2; ++t) {
        const int nb = m * 2 + t;
        short8 b[4];
#pragma unroll
        for (int kb = 0; kb < 4; ++kb)
          b[kb] = *(const short8*)(lw1 + ((nb * 4 + kb) * 64 + lane) * 8);
#pragma unroll
        for (int r = 0; r < 2; ++r) {
          f32x4 acc = {0.f, 0.f, 0.f, 0.f};
#pragma unroll
          for (int kb = 0; kb < 4; ++kb)
            acc = __builtin_amdgcn_mfma_f32_16x16x32_bf16(afr[r][kb], b[kb], acc, 0, 0, 0);
#pragma unroll
          for (int j = 0; j < 4; ++j) {
            float h = acc[j];
            ssum[nb] += h;
            ssq[nb] += h * h;
            int p = l4 * 4 + j;
            int cp = t * 16 + l15;
            int slot = ((cp >> 3) ^ (p >> 2)) & 3;
            mys[r * 512 + p * 32 + slot * 8 + (cp & 7)] = bfc(h);
          }
        }
      }
      // transpose read-back + h1b store for chunk m, 2 row-tiles
#pragma unroll
      for (int r = 0; r < 2; ++r) {
        short8 hf = *(const short8*)(mys + r * 512 + l15 * 32 + rslot * 8);
        *(short8*)(h1b + ((size_t)((rg0 + r) * 4 + m) * 64 + lane) * 8) = hf;
      }
    }
  }

  // stats reduction
#pragma unroll
  for (int nb = 0; nb < 8; ++nb) {
    float a = ssum[nb], b = ssq[nb];
    a += __shfl_xor(a, 16, 64); a += __shfl_xor(a, 32, 64);
    b += __shfl_xor(b, 16, 64); b += __shfl_xor(b, 32, 64);
    if (l4 == 0) {
      int c = nb * 16 + l15;
      redu[(wave * 128 + c) * 2 + 0] = a;
      redu[(wave * 128 + c) * 2 + 1] = b;
    }
  }
  __syncthreads();
  if (tid < 128) {
    float s = 0.f, q = 0.f;
#pragma unroll
    for (int w = 0; w < 4; ++w) {
      s += redu[(w * 128 + tid) * 2 + 0];
      q += redu[(w * 128 + tid) * 2 + 1];
    }
    int split = blockIdx.x & (NSPLIT - 1);
    atomicAdd(&gstats[split * 128 + tid], s);
    atomicAdd(&gstats[NSPLIT * 128 + split * 128 + tid], q);
  }
}

// ---- shared Phase-A converter: h1b frags -> a1 frags (bn1 + lrelu) ----
template <int NR>
__device__ __forceinline__ void load_a1(const short* __restrict__ h1b,
                                        const float* __restrict__ ls,
                                        int rgbase, int lane, int l4,
                                        short8 a1[NR][4]) {
#pragma unroll
  for (int kb = 0; kb < 4; ++kb) {
    const int c0 = kb * 32 + l4 * 8;
    f32x4 sa0 = *(const f32x4*)&ls[c0];
    f32x4 sa1 = *(const f32x4*)&ls[c0 + 4];
    f32x4 sb0 = *(const f32x4*)&ls[128 + c0];
    f32x4 sb1 = *(const f32x4*)&ls[128 + c0 + 4];
#pragma unroll
    for (int r = 0; r < NR; ++r) {
      short8 h = *(const short8*)(h1b + ((size_t)((rgbase + r) * 4 + kb) * 64 + lane) * 8);
      short8 a;
#pragma unroll
      for (int u = 0; u < 4; ++u) {
        float t = bf2f(h[u]) * sa0[u] + sb0[u];
        a[u] = bfc(fmaxf(t, 0.01f * t));
      }
#pragma unroll
      for (int u = 0; u < 4; ++u) {
        float t = bf2f(h[4 + u]) * sa1[u] + sb1[u];
        a[4 + u] = bfc(fmaxf(t, 0.01f * t));
      }
      a1[r][kb] = a;
    }
  }
}

// ---- P2: a1 = lrelu(bn1(h1)); h2 = a1 @ w2^T; stats of h2 (row-pair) ----
__global__ __launch_bounds__(256, 2) void k_p2(
    const short* __restrict__ h1b, const short* __restrict__ wp2,
    const float* __restrict__ scale1, const float* __restrict__ shift1,
    float* __restrict__ gstats) {
  __shared__ short lw2[16384];          // 32 KB
  __shared__ float ls[256];             // scale1 | shift1
  __shared__ float redu[4 * 128 * 2];   // 4 KB

  const int tid = threadIdx.x;
  const int lane = tid & 63;
  const int wave = tid >> 6;
  const int l15 = lane & 15;
  const int l4 = lane >> 4;

  {
    const int4* sp = (const int4*)wp2;
    int4* dp = (int4*)lw2;
    for (int i = tid; i < 2048; i += 256) dp[i] = sp[i];
    if (tid < 128) { ls[tid] = scale1[tid]; ls[128 + tid] = shift1[tid]; }
  }
  __syncthreads();

  float ssum[8], ssq[8];
#pragma unroll
  for (int nb = 0; nb < 8; ++nb) { ssum[nb] = 0.f; ssq[nb] = 0.f; }

  const int rgbase = blockIdx.x * 16 + wave * 4;

#pragma unroll
  for (int bt = 0; bt < 2; ++bt) {
    const int rg0 = rgbase + bt * 2;
    short8 a1[2][4];
    load_a1<2>(h1b, ls, rg0, lane, l4, a1);

#pragma unroll
    for (int nb = 0; nb < 8; ++nb) {
      short8 b[4];
#pragma unroll
      for (int kb = 0; kb < 4; ++kb)
        b[kb] = *(const short8*)(lw2 + ((nb * 4 + kb) * 64 + lane) * 8);
#pragma unroll
      for (int r = 0; r < 2; ++r) {
        f32x4 acc = {0.f, 0.f, 0.f, 0.f};
#pragma unroll
        for (int kb = 0; kb < 4; ++kb)
          acc = __builtin_amdgcn_mfma_f32_16x16x32_bf16(a1[r][kb], b[kb], acc, 0, 0, 0);
#pragma unroll
        for (int j = 0; j < 4; ++j) {
          float h = acc[j];
          ssum[nb] += h;
          ssq[nb] += h * h;
        }
      }
    }
  }

#pragma unroll
  for (int nb = 0; nb < 8; ++nb) {
    float a = ssum[nb], b = ssq[nb];
    a += __shfl_xor(a, 16, 64); a += __shfl_xor(a, 32, 64);
    b += __shfl_xor(b, 16, 64); b += __shfl_xor(b, 32, 64);
    if (l4 == 0) {
      int c = nb * 16 + l15;
      redu[(wave * 128 + c) * 2 + 0] = a;
      redu[(wave * 128 + c) * 2 + 1] = b;
    }
  }
  __syncthreads();
  if (tid < 128) {
    float s = 0.f, q = 0.f;
#pragma unroll
    for (int w = 0; w < 4; ++w) {
      s += redu[(w * 128 + tid) * 2 + 0];
      q += redu[(w * 128 + tid) * 2 + 1];
    }
    int split = blockIdx.x & (NSPLIT - 1);
    atomicAdd(&gstats[2 * NSPLIT * 128 + split * 128 + tid], s);
    atomicAdd(&gstats[3 * NSPLIT * 128 + split * 128 + tid], q);
  }
}

// ---- P3 full (row-pair, round-8-verified body): out = max over s ----
__global__ __launch_bounds__(256, 2) void k_p3f(
    const short* __restrict__ h1b, const short* __restrict__ xbf,
    const short* __restrict__ wp2s,
    const float* __restrict__ scale1, const float* __restrict__ shift1,
    const float* __restrict__ shift2, float* __restrict__ out) {
  __shared__ short lw[16384];           // 32 KB (s2-baked w2 frags)
  __shared__ float lsf[384];            // scale1 | shift1 | sh2

  const int tid = threadIdx.x;
  const int lane = tid & 63;
  const int wave = tid >> 6;
  const int l15 = lane & 15;
  const int l4 = lane >> 4;

  {
    const int4* sp = (const int4*)wp2s;
    int4* dp = (int4*)lw;
    for (int i = tid; i < 2048; i += 256) dp[i] = sp[i];
    if (tid < 128) {
      lsf[tid] = scale1[tid];
      lsf[128 + tid] = shift1[tid];
      lsf[256 + tid] = shift2[tid];
    }
  }
  __syncthreads();

  // identity B-fragments (bf16 1.0 = 0x3F80); nb even hit u=l15-8*l4, odd +16
  const int he = l15 - l4 * 8;
  const int ho = l15 + 16 - l4 * 8;
  short8 idE, idO;
#pragma unroll
  for (int u = 0; u < 8; ++u) {
    idE[u] = (he == u) ? (short)0x3F80 : (short)0;
    idO[u] = (ho == u) ? (short)0x3F80 : (short)0;
  }

  const int rgbase = (blockIdx.x * 256 + wave * 64) >> 4;
  const int bn0 = (blockIdx.x * 256 + wave * 64) >> 5;

#pragma unroll
  for (int pr = 0; pr < 2; ++pr) {
    const int rg0 = rgbase + pr * 2;

    short8 a1[2][4], xa[2][4];
#pragma unroll
    for (int r = 0; r < 2; ++r) {
#pragma unroll
      for (int kb = 0; kb < 4; ++kb)
        xa[r][kb] = *(const short8*)(xbf + ((size_t)((rg0 + r) * 4 + kb) * 64 + lane) * 8);
    }
    load_a1<2>(h1b, lsf, rg0, lane, l4, a1);

    float om[8];
#pragma unroll
    for (int nb = 0; nb < 8; ++nb) om[nb] = -3.4e38f;

#pragma unroll
    for (int nb = 0; nb < 8; ++nb) {
      short8 b[4];
#pragma unroll
      for (int kb = 0; kb < 4; ++kb)
        b[kb] = *(const short8*)(lw + ((nb * 4 + kb) * 64 + lane) * 8);
      const float sh = lsf[256 + nb * 16 + l15];
#pragma unroll
      for (int r = 0; r < 2; ++r) {
        f32x4 acc = {0.f, 0.f, 0.f, 0.f};
#pragma unroll
        for (int kb = 0; kb < 4; ++kb)
          acc = __builtin_amdgcn_mfma_f32_16x16x32_bf16(a1[r][kb], b[kb], acc, 0, 0, 0);
        acc = __builtin_amdgcn_mfma_f32_16x16x32_bf16(
            xa[r][nb >> 1], (nb & 1) ? idO : idE, acc, 0, 0, 0);
#pragma unroll
        for (int j = 0; j < 4; ++j) {
          float v = acc[j] + sh;
          v = fmaxf(v, 0.01f * v);
          om[nb] = fmaxf(om[nb], v);
        }
      }
    }

#pragma unroll
    for (int nb = 0; nb < 8; ++nb) {
      float m = om[nb];
      m = fmaxf(m, __shfl_xor(m, 16, 64));
      m = fmaxf(m, __shfl_xor(m, 32, 64));
      if (l4 == 0) out[(size_t)(bn0 + pr) * 128 + nb * 16 + l15] = m;
    }
  }
}

// ---- P3 mid-tier fallback (round-3 proven) ----
__global__ __launch_bounds__(256, 2) void k_p3m(
    const float* __restrict__ x, const short* __restrict__ h1b,
    const short* __restrict__ wp2,
    const float* __restrict__ scale1, const float* __restrict__ shift1,
    const float* __restrict__ scale2, const float* __restrict__ shift2,
    float* __restrict__ out) {
  __shared__ short lw2[16384];
  __shared__ float ls1[256];
  __shared__ float ls2[256];

  const int tid = threadIdx.x;
  const int lane = tid & 63;
  const int wave = tid >> 6;
  const int l15 = lane & 15;
  const int l4 = lane >> 4;

  {
    const int4* sp = (const int4*)wp2;
    int4* dp = (int4*)lw2;
    for (int i = tid; i < 2048; i += 256) dp[i] = sp[i];
    if (tid < 128) {
      ls1[tid] = scale1[tid];
      ls1[128 + tid] = shift1[tid];
      ls2[tid] = scale2[tid];
      ls2[128 + tid] = shift2[tid];
    }
  }
  __syncthreads();

  float om0[8], om1[8];
#pragma unroll
  for (int nb = 0; nb < 8; ++nb) { om0[nb] = -3.4e38f; om1[nb] = -3.4e38f; }

  const int rowblk = blockIdx.x * 256;

  for (int rt = 0; rt < 4; ++rt) {
    const int row0 = rowblk + wave * 64 + rt * 16;
    const int rg = row0 >> 4;
    short8 a1[4];
#pragma unroll
    for (int kb = 0; kb < 4; ++kb) {
      short8 h = *(const short8*)(h1b + ((size_t)(rg * 4 + kb) * 64 + lane) * 8);
      const int c0 = kb * 32 + l4 * 8;
      f32x4 sa0 = *(const f32x4*)&ls1[c0];
      f32x4 sa1 = *(const f32x4*)&ls1[c0 + 4];
      f32x4 sb0 = *(const f32x4*)&ls1[128 + c0];
      f32x4 sb1 = *(const f32x4*)&ls1[128 + c0 + 4];
      short8 a;
#pragma unroll
      for (int u = 0; u < 4; ++u) {
        float v = bf2f(h[u]) * sa0[u] + sb0[u];
        v = v > 0.f ? v : 0.01f * v;
        a[u] = f2bf(v);
      }
#pragma unroll
      for (int u = 0; u < 4; ++u) {
        float v = bf2f(h[4 + u]) * sa1[u] + sb1[u];
        v = v > 0.f ? v : 0.01f * v;
        a[4 + u] = f2bf(v);
      }
      a1[kb] = a;
    }
#pragma unroll
    for (int nb = 0; nb < 8; ++nb) {
      f32x4 acc = {0.f, 0.f, 0.f, 0.f};
#pragma unroll
      for (int kb = 0; kb < 4; ++kb) {
        short8 b = *(const short8*)(lw2 + ((nb * 4 + kb) * 64 + lane) * 8);
        acc = __builtin_amdgcn_mfma_f32_16x16x32_bf16(a1[kb], b, acc, 0, 0, 0);
      }
      const float sc = ls2[nb * 16 + l15];
      const float sh = ls2[128 + nb * 16 + l15];
#pragma unroll
      for (int j = 0; j < 4; ++j) {
        int p = l4 * 4 + j;
        float xr = x[(size_t)(row0 + p) * 128 + nb * 16 + l15];
        float v = acc[j] * sc + sh + xr;
        v = v > 0.f ? v : 0.01f * v;
        if (rt < 2) om0[nb] = fmaxf(om0[nb], v);
        else        om1[nb] = fmaxf(om1[nb], v);
      }
    }
  }

  const int bn0 = (rowblk + wave * 64) >> 5;
#pragma unroll
  for (int nb = 0; nb < 8; ++nb) {
    float m0 = om0[nb], m1 = om1[nb];
    m0 = fmaxf(m0, __shfl_xor(m0, 16, 64)); m0 = fmaxf(m0, __shfl_xor(m0, 32, 64));
    m1 = fmaxf(m1, __shfl_xor(m1, 16, 64)); m1 = fmaxf(m1, __shfl_xor(m1, 32, 64));
    int c = nb * 16 + l15;
    if (l4 == 0)      out[(size_t)bn0 * 128 + c] = m0;
    else if (l4 == 1) out[(size_t)(bn0 + 1) * 128 + c] = m1;
  }
}

// =======================  FALLBACK (round-1 proven path)  =======================
template <int PHASE>
__global__ __launch_bounds__(256, 2) void k_gemm(
    const float* __restrict__ x,
    const short* __restrict__ wp1, const short* __restrict__ wp2,
    const float* __restrict__ scale1, const float* __restrict__ shift1,
    const float* __restrict__ scale2, const float* __restrict__ shift2,
    float* __restrict__ gstats, float* __restrict__ out) {
  __shared__ short lw1[16384];
  __shared__ short lw2[(PHASE >= 2) ? 16384 : 16];
  __shared__ short stripes[(PHASE >= 2) ? 8192 : 2048];

  const int tid = threadIdx.x;
  const int lane = tid & 63;
  const int wave = tid >> 6;
  const int l15 = lane & 15;
  const int l4 = lane >> 4;

  {
    const int4* s1p = (const int4*)wp1;
    int4* d1p = (int4*)lw1;
    for (int i = tid; i < 2048; i += 256) d1p[i] = s1p[i];
    if (PHASE >= 2) {
      const int4* s2p = (const int4*)wp2;
      int4* d2p = (int4*)lw2;
      for (int i = tid; i < 2048; i += 256) d2p[i] = s2p[i];
    }
  }
  __syncthreads();

  float s1[8], sh1[8], s2[8], sh2[8];
  if (PHASE >= 2) {
#pragma unroll
    for (int nb = 0; nb < 8; ++nb) {
      s1[nb] = scale1[nb * 16 + l15];
      sh1[nb] = shift1[nb * 16 + l15];
    }
  }
  if (PHASE == 3) {
#pragma unroll
    for (int nb = 0; nb < 8; ++nb) {
      s2[nb] = scale2[nb * 16 + l15];
      sh2[nb] = shift2[nb * 16 + l15];
    }
  }

  float ssum[8], ssq[8], om0[8], om1[8];
#pragma unroll
  for (int nb = 0; nb < 8; ++nb) {
    ssum[nb] = 0.f; ssq[nb] = 0.f;
    om0[nb] = -3.4e38f; om1[nb] = -3.4e38f;
  }

  char* mystripe = (char*)(stripes) + wave * 4096;
  const int rowblk = blockIdx.x * 256;

  for (int rt = 0; rt < 4; ++rt) {
    const int row0 = rowblk + wave * 64 + rt * 16;
    short8 afr[4];
    const float* xrow = x + (size_t)(row0 + l15) * 128 + l4 * 8;
#pragma unroll
    for (int kb = 0; kb < 4; ++kb) {
      float4 v0 = *(const float4*)(xrow + kb * 32);
      float4 v1 = *(const float4*)(xrow + kb * 32 + 4);
      short8 a;
      a[0] = f2bf(v0.x); a[1] = f2bf(v0.y); a[2] = f2bf(v0.z); a[3] = f2bf(v0.w);
      a[4] = f2bf(v1.x); a[5] = f2bf(v1.y); a[6] = f2bf(v1.z); a[7] = f2bf(v1.w);
      afr[kb] = a;
    }
#pragma unroll
    for (int nb = 0; nb < 8; ++nb) {
      f32x4 acc = {0.f, 0.f, 0.f, 0.f};
#pragma unroll
      for (int kb = 0; kb < 4; ++kb) {
        short8 b = *(const short8*)(lw1 + ((nb * 4 + kb) * 64 + lane) * 8);
        acc = __builtin_amdgcn_mfma_f32_16x16x32_bf16(afr[kb], b, acc, 0, 0, 0);
      }
      if (PHASE == 1) {
#pragma unroll
        for (int j = 0; j < 4; ++j) {
          float h = acc[j];
          ssum[nb] += h;
          ssq[nb] += h * h;
        }
      } else {
#pragma unroll
        for (int j = 0; j < 4; ++j) {
          float v = acc[j] * s1[nb] + sh1[nb];
          v = v > 0.f ? v : 0.01f * v;
          int p = l4 * 4 + j;
          int cb = (nb * 16 + l15) * 2;
          int off = (p << 8) | ((((cb >> 4) ^ (p & 7)) << 4) | (cb & 15));
          *(short*)(mystripe + off) = f2bf(v);
        }
      }
    }
    if (PHASE >= 2) {
      short8 a2[4];
#pragma unroll
      for (int kb = 0; kb < 4; ++kb) {
        int chunk = (kb * 4 + l4) ^ (l15 & 7);
        int off = (l15 << 8) | (chunk << 4);
        a2[kb] = *(const short8*)(mystripe + off);
      }
#pragma unroll
      for (int nb = 0; nb < 8; ++nb) {
        f32x4 acc = {0.f, 0.f, 0.f, 0.f};
#pragma unroll
        for (int kb = 0; kb < 4; ++kb) {
          short8 b = *(const short8*)(lw2 + ((nb * 4 + kb) * 64 + lane) * 8);
          acc = __builtin_amdgcn_mfma_f32_16x16x32_bf16(a2[kb], b, acc, 0, 0, 0);
        }
        if (PHASE == 2) {
#pragma unroll
          for (int j = 0; j < 4; ++j) {
            float h = acc[j];
            ssum[nb] += h;
            ssq[nb] += h * h;
          }
        } else {
#pragma unroll
          for (int j = 0; j < 4; ++j) {
            int p = l4 * 4 + j;
            float xr = x[(size_t)(row0 + p) * 128 + nb * 16 + l15];
            float v = acc[j] * s2[nb] + sh2[nb] + xr;
            v = v > 0.f ? v : 0.01f * v;
            if (rt < 2) om0[nb] = fmaxf(om0[nb], v);
            else        om1[nb] = fmaxf(om1[nb], v);
          }
        }
      }
    }
  }

  if (PHASE <= 2) {
    __syncthreads();
    float* redu = (float*)stripes;
#pragma unroll
    for (int nb = 0; nb < 8; ++nb) {
      float a = ssum[nb], b = ssq[nb];
      a += __shfl_xor(a, 16, 64); a += __shfl_xor(a, 32, 64);
      b += __shfl_xor(b, 16, 64); b += __shfl_xor(b, 32, 64);
      if (l4 == 0) {
        int c = nb * 16 + l15;
        redu[(wave * 128 + c) * 2 + 0] = a;
        redu[(wave * 128 + c) * 2 + 1] = b;
      }
    }
    __syncthreads();
    if (tid < 128) {
      float s = 0.f, q = 0.f;
#pragma unroll
      for (int w = 0; w < 4; ++w) {
        s += redu[(w * 128 + tid) * 2 + 0];
        q += redu[(w * 128 + tid) * 2 + 1];
      }
      int split = blockIdx.x & (NSPLIT - 1);
      int base = (PHASE == 1 ? 0 : 2) * NSPLIT * 128;
      atomicAdd(&gstats[base + split * 128 + tid], s);
      atomicAdd(&gstats[base + NSPLIT * 128 + split * 128 + tid], q);
    }
  } else {
    const int bn0 = (rowblk + wave * 64) >> 5;
#pragma unroll
    for (int nb = 0; nb < 8; ++nb) {
      float m0 = om0[nb], m1 = om1[nb];
      m0 = fmaxf(m0, __shfl_xor(m0, 16, 64)); m0 = fmaxf(m0, __shfl_xor(m0, 32, 64));
      m1 = fmaxf(m1, __shfl_xor(m1, 16, 64)); m1 = fmaxf(m1, __shfl_xor(m1, 32, 64));
      int c = nb * 16 + l15;
      if (l4 == 0)      out[(size_t)bn0 * 128 + c] = m0;
      else if (l4 == 1) out[(size_t)(bn0 + 1) * 128 + c] = m1;
    }
  }
}

extern "C" void kernel_launch(void* const* d_in, const int* in_sizes, int n_in,
                              void* d_out, int out_size, void* d_ws, size_t ws_size,
                              hipStream_t stream) {
  const float* x   = (const float*)d_in[0];
  const float* w1  = (const float*)d_in[1];
  const float* g1  = (const float*)d_in[3];
  const float* be1 = (const float*)d_in[4];
  const float* w2  = (const float*)d_in[5];
  const float* g2  = (const float*)d_in[7];
  const float* be2 = (const float*)d_in[8];
  float* out = (float*)d_out;

  char* ws = (char*)d_ws;
  short* wp1  = (short*)ws;                        // 32 KB
  short* wp2  = (short*)(ws + 32768);              // 32 KB
  short* wp2s = (short*)(ws + 65536);              // 32 KB (s2-baked)
  float* gstats = (float*)(ws + 98304);            // 128 KB
  float* scale1 = (float*)(ws + 98304 + 131072);   // 512 floats: s1|sh1|s2|sh2
  float* shift1 = scale1 + 128;
  float* scale2 = scale1 + 256;
  float* shift2 = scale1 + 384;
  const size_t H1B = (size_t)NPTS * 128 * 2;       // 134,217,728 B
  short* h1b = (short*)(ws + 262144);
  short* xbf = (short*)(ws + 262144 + H1B);

  const size_t need_full = 262144 + 2 * H1B;
  const size_t need_mid  = 262144 + H1B;

  k_prep<<<256, 256, 0, stream>>>(w1, w2, wp1, wp2, gstats);

  if (ws_size >= need_full) {
    k_p1<1><<<NPTS / 256, 256, 0, stream>>>(x, wp1, h1b, xbf, gstats);
    k_finalize<<<1, 128, 0, stream>>>(gstats, gstats + NSPLIT * 128, g1, be1,
                                      scale1, shift1);
    k_p2<<<NPTS / 256, 256, 0, stream>>>(h1b, wp2, scale1, shift1, gstats);
    k_finalize2x<<<1, 128, 0, stream>>>(gstats + 2 * NSPLIT * 128,
                                        gstats + 3 * NSPLIT * 128, g2, be2,
                                        w2, scale2, shift2, wp2s);
    k_p3f<<<NPTS / 256, 256, 0, stream>>>(h1b, xbf, wp2s, scale1, shift1,
                                          shift2, out);
  } else if (ws_size >= need_mid) {
    k_p1<0><<<NPTS / 256, 256, 0, stream>>>(x, wp1, h1b, (short*)0, gstats);
    k_finalize<<<1, 128, 0, stream>>>(gstats, gstats + NSPLIT * 128, g1, be1,
                                      scale1, shift1);
    k_p2<<<NPTS / 256, 256, 0, stream>>>(h1b, wp2, scale1, shift1, gstats);
    k_finalize<<<1, 128, 0, stream>>>(gstats + 2 * NSPLIT * 128,
                                      gstats + 3 * NSPLIT * 128, g2, be2,
                                      scale2, shift2);
    k_p3m<<<NPTS / 256, 256, 0, stream>>>(x, h1b, wp2, scale1, shift1,
                                          scale2, shift2, out);
  } else {
    k_gemm<1><<<NPTS / 256, 256, 0, stream>>>(x, wp1, wp2, scale1, shift1,
                                              scale2, shift2, gstats, out);
    k_finalize<<<1, 128, 0, stream>>>(gstats, gstats + NSPLIT * 128, g1, be1,
                                      scale1, shift1);
    k_gemm<2><<<NPTS / 256, 256, 0, stream>>>(x, wp1, wp2, scale1, shift1,
                                              scale2, shift2, gstats, out);
    k_finalize<<<1, 128, 0, stream>>>(gstats + 2 * NSPLIT * 128,
                                      gstats + 3 * NSPLIT * 128, g2, be2,
                                      scale2, shift2);
    k_gemm<3><<<NPTS / 256, 256, 0, stream>>>(x, wp1, wp2, scale1, shift1,
                                              scale2, shift2, gstats, out);
  }
}